// Round 14
// baseline (298.426 us; speedup 1.0000x reference)
//
#include <hip/hip_runtime.h>

using u16 = unsigned short;
using s16x8 = __attribute__((ext_vector_type(8))) short;   // 8 bf16 (4 VGPRs)
using f32x4 = __attribute__((ext_vector_type(4))) float;

#define DEVI __device__ __forceinline__

constexpr int AN = 9, NB = 10, NN = 4096, DORI = 2048, DAPP = 512, NCLS = 21, QCOLS = 160;

// output offsets (f32 elements) in return order
constexpr size_t O0 = 0;                 // output            (4096,4)
constexpr size_t O1 = 16384;             // output_beta       (4096,4)
constexpr size_t O2 = 32768;             // alpha_softmax     (9,4096,4)
constexpr size_t O3 = 180224;            // beta_softmax      (9,4096,4)
constexpr size_t O4 = 327680;            // delta_pred_offset (9,4096,4)
constexpr size_t O5 = 475136;            // delta_pred_offset (9,4096,4)
constexpr size_t O6 = 622592;            // alpha             (9,4096,4)
constexpr size_t O7 = 770048;            // beta_out          (9,4096,4)
constexpr size_t O8 = 917504;            // cls_score         (9,4096,21)
constexpr size_t O9 = 1691648;           // alpha_softmax_cls (9,4096,1)
constexpr size_t O10 = 1728512;          // beta_softmax_cls
constexpr size_t O11 = 1765376;          // alpha_cls
constexpr size_t O12 = 1802240;          // beta_out_cls

// prep_cast block ranges
constexpr int CAST_B = 36864;            // AN*NN*DORI/8/256
constexpr int ATT_B  = 256;              // (2048/64)*(512/64)
constexpr int PQ_B   = 3200;             // NB*QCOLS*DAPP/256
constexpr int PS_B   = 72;               // AN*DORI/256
constexpr int GT_B   = 4096;             // NN*DORI/8/256
constexpr int PREP_TOTAL = CAST_B + ATT_B + PQ_B + PS_B + GT_B;   // 44488

DEVI u16 f2b(float f) {                   // f32 -> bf16 RNE (internal use only)
  unsigned u = __float_as_uint(f);
  unsigned r = (u + 0x7fffu + ((u >> 16) & 1u)) >> 16;
  return (u16)r;
}

DEVI uint4 pack8(float4 u, float4 v) {    // 8 f32 -> 8 bf16 packed
  uint4 r;
  r.x = (unsigned)f2b(u.x) | ((unsigned)f2b(u.y) << 16);
  r.y = (unsigned)f2b(u.z) | ((unsigned)f2b(u.w) << 16);
  r.z = (unsigned)f2b(v.x) | ((unsigned)f2b(v.y) << 16);
  r.w = (unsigned)f2b(v.z) | ((unsigned)f2b(v.w) << 16);
  return r;
}

DEVI void gload_lds16(const u16* g, u16* l) {   // 16B global -> LDS direct
  __builtin_amdgcn_global_load_lds(
      (const __attribute__((address_space(1))) void*)g,
      (__attribute__((address_space(3))) void*)l, 16, 0, 0);
}

// ================= prep_cast: cast | att-transpose | pack_q | pack_small | gt ======
__global__ __launch_bounds__(256) void prep_cast(const float* __restrict__ features,
                                                 const float* __restrict__ att,
                                                 const float* __restrict__ wq,
                                                 const float* __restrict__ wqc,
                                                 const float* __restrict__ wk,
                                                 const float* __restrict__ wkc,
                                                 const float* __restrict__ aw,
                                                 const float* __restrict__ bb,
                                                 const float* __restrict__ awc,
                                                 const float* __restrict__ cw,
                                                 const float* __restrict__ gt,
                                                 u16* __restrict__ featB,
                                                 u16* __restrict__ attB,
                                                 u16* __restrict__ Wq,
                                                 u16* __restrict__ Wsm) {
  __shared__ float tile[64][65];
  const int b = blockIdx.x, tid = threadIdx.x;
  if (b < CAST_B) {                                 // features f32 -> featB[0..8]
    if (!featB) return;
    long i = (long)b * 256 + tid;
    float4 v0 = ((const float4*)features)[i * 2];
    float4 v1 = ((const float4*)features)[i * 2 + 1];
    ((uint4*)featB)[i] = pack8(v0, v1);
  } else if (b < CAST_B + ATT_B) {                  // attB[c][d] = att[d][c], LDS tile
    int b2 = b - CAST_B;
    int d0 = (b2 >> 3) * 64, c0 = (b2 & 7) * 64;
#pragma unroll
    for (int r = 0; r < 16; ++r) {
      int dl = r * 4 + (tid >> 6), cl = tid & 63;
      tile[dl][cl] = att[(size_t)(d0 + dl) * DAPP + c0 + cl];
    }
    __syncthreads();
#pragma unroll
    for (int w = 0; w < 16; ++w) {
      int cl = w * 4 + (tid >> 6), dl = tid & 63;
      attB[(size_t)(c0 + cl) * DORI + d0 + dl] = f2b(tile[dl][cl]);
    }
  } else if (b < CAST_B + ATT_B + PQ_B) {           // Wq[b][160][512]
    int t = (b - CAST_B - ATT_B) * 256 + tid;
    int bq = t / (QCOLS * DAPP);
    int r = t % (QCOLS * DAPP);
    int col = r / DAPP, d = r % DAPP;
    float v;
    if (bq < 9) {
      if (col < 128) v = wq[(size_t)bq * DAPP * 128 + (size_t)d * 128 + col];
      else           v = wqc[(size_t)bq * DAPP * 32 + (size_t)d * 32 + (col - 128)];
    } else {
      if (col < 128) v = wk[(size_t)d * 128 + col];
      else           v = wkc[(size_t)d * 32 + (col - 128)];
    }
    Wq[t] = f2b(v);
  } else if (b < CAST_B + ATT_B + PQ_B + PS_B) {    // Wsmall[a][32][2048]
    int t = (b - CAST_B - ATT_B - PQ_B) * 256 + tid;
    if (t >= AN * DORI) return;
    int a = t / DORI, f = t % DORI;
    u16* Wa = Wsm + (size_t)a * 32 * DORI;
    for (int c = 0; c < 4; ++c)  Wa[c * DORI + f]       = f2b(aw[((size_t)a * DORI + f) * 4 + c]);
    for (int c = 0; c < 4; ++c)  Wa[(4 + c) * DORI + f] = f2b(bb[((size_t)a * DORI + f) * 4 + c]);
    for (int c = 0; c < 21; ++c) Wa[(8 + c) * DORI + f] = f2b(cw[((size_t)a * DORI + f) * 21 + c]);
    Wa[29 * DORI + f] = f2b(awc[(size_t)a * DORI + f]);
    Wa[30 * DORI + f] = 0;
    Wa[31 * DORI + f] = 0;
  } else {                                          // gt_features -> featB[9]
    if (!featB) return;
    long i = (long)(b - CAST_B - ATT_B - PQ_B - PS_B) * 256 + tid;
    float4 v0 = ((const float4*)gt)[i * 2];
    float4 v1 = ((const float4*)gt)[i * 2 + 1];
    ((uint4*)(featB + (size_t)AN * NN * DORI))[i] = pack8(v0, v1);
  }
}

// ================= gemm_main: BM=256, BK=64, panel-local XCD swizzle ===============
// grid (5, 16, 10), 512 threads / 8 waves; bx<4: off 256x128 (wave 64x64),
// bx==4: smallf 256x32 (wave 32x32). 25600 barrier pairs (half of BK=64@BM=128).
// LDS [row][64], chunk swizzle kc^(row&7) both-sides (rule 21). Panel-local XCD
// mapping: the 5 bx blocks sharing one A-panel run back-to-back on ONE XCD.
__global__ __launch_bounds__(512) void gemm_main(const u16* __restrict__ featB,
                                                 const u16* __restrict__ attB,
                                                 const u16* __restrict__ Wsm,
                                                 u16* __restrict__ offb,
                                                 float* __restrict__ smallf,
                                                 float* __restrict__ cls_out) {
  __shared__ __align__(16) u16 As[256 * 64];   // 32 KB
  __shared__ __align__(16) u16 Bs[128 * 64];   // 16 KB

  int bx, by, bz;
  {                                   // panel-local XCD swizzle (800 blocks = 8*100)
    int h = blockIdx.x + 5 * (blockIdx.y + 16 * blockIdx.z);
    int x = h & 7, m = h >> 3;        // x = XCD, m in [0,100)
    bx = m % 5;
    int p = (m / 5) * 8 + x;          // panel in [0,160), p&7 == XCD
    by = p & 15; bz = p >> 4;
  }
  const int tid = threadIdx.x, lane = tid & 63, w = tid >> 6;
  const bool small = (bx == 4);
  if (small && bz == 9) return;       // no small path for gt batch
  const int tileM = by * 256;
  const u16* Ab = featB + ((size_t)bz * NN + tileM) * DORI;
  const u16* Bb = small ? (Wsm + (size_t)bz * 32 * DORI)
                        : (attB + (size_t)bx * 128 * DORI);

  f32x4 accM[4][4], accS[2][2];
#pragma unroll
  for (int i = 0; i < 4; ++i)
#pragma unroll
    for (int j = 0; j < 4; ++j) accM[i][j] = (f32x4){0.f, 0.f, 0.f, 0.f};
#pragma unroll
  for (int i = 0; i < 2; ++i)
#pragma unroll
    for (int j = 0; j < 2; ++j) accS[i][j] = (f32x4){0.f, 0.f, 0.f, 0.f};

  const int wm = w & 3, wn = w >> 2;   // off: 4 M-waves x 2 N-waves, 64x64 each

  // stage swizzle: chunk c -> row = c>>3, phys = c&7, logical kc = phys ^ (row&7)
  int arow[4], acol[4];
#pragma unroll
  for (int i = 0; i < 4; ++i) {                     // A: 2048 chunks / 512 thr
    int c = tid + i * 512;
    arow[i] = c >> 3;
    acol[i] = (((c & 7) ^ ((c >> 3) & 7))) * 8;
  }
  // read swizzle: row&7 = lane&7; logical chunk lc = mk*4 + (lane>>4); phys = lc^(lane&7)
  const int lanerow = (lane & 15) * 64;
  const int ph0 = (((lane >> 4)) ^ (lane & 7)) * 8;        // mk = 0
  const int ph1 = (((lane >> 4) + 4) ^ (lane & 7)) * 8;    // mk = 1

  for (int k0 = 0; k0 < DORI; k0 += 64) {
#pragma unroll
    for (int i = 0; i < 4; ++i)
      gload_lds16(Ab + (size_t)arow[i] * DORI + k0 + acol[i], As + (tid + i * 512) * 8);
    if (small) {
      if (tid < 256)                                // B: 32 rows x 8 chunks
        gload_lds16(Bb + (size_t)(tid >> 3) * DORI + k0 + (((tid & 7) ^ ((tid >> 3) & 7)) * 8),
                    Bs + tid * 8);
    } else {
#pragma unroll
      for (int i = 0; i < 2; ++i) {                 // B: 1024 chunks / 512 thr
        int c = tid + i * 512;
        gload_lds16(Bb + (size_t)(c >> 3) * DORI + k0 + ((((c & 7) ^ ((c >> 3) & 7))) * 8),
                    Bs + c * 8);
      }
    }
    __syncthreads();
    if (small) {
#pragma unroll
      for (int mk = 0; mk < 2; ++mk) {
        const int ph = mk ? ph1 : ph0;
        s16x8 af[2], bf[2];
#pragma unroll
        for (int i = 0; i < 2; ++i)
          af[i] = *(const s16x8*)(As + (w * 32 + i * 16) * 64 + lanerow + ph);
#pragma unroll
        for (int j = 0; j < 2; ++j)
          bf[j] = *(const s16x8*)(Bs + (j * 16) * 64 + lanerow + ph);
#pragma unroll
        for (int i = 0; i < 2; ++i)
#pragma unroll
          for (int j = 0; j < 2; ++j)
            accS[i][j] = __builtin_amdgcn_mfma_f32_16x16x32_bf16(af[i], bf[j], accS[i][j], 0, 0, 0);
      }
    } else {
#pragma unroll
      for (int mk = 0; mk < 2; ++mk) {
        const int ph = mk ? ph1 : ph0;
        s16x8 af[4], bf[4];
#pragma unroll
        for (int i = 0; i < 4; ++i)
          af[i] = *(const s16x8*)(As + (wm * 64 + i * 16) * 64 + lanerow + ph);
#pragma unroll
        for (int j = 0; j < 4; ++j)
          bf[j] = *(const s16x8*)(Bs + (wn * 64 + j * 16) * 64 + lanerow + ph);
#pragma unroll
        for (int i = 0; i < 4; ++i)
#pragma unroll
          for (int j = 0; j < 4; ++j)
            accM[i][j] = __builtin_amdgcn_mfma_f32_16x16x32_bf16(af[i], bf[j], accM[i][j], 0, 0, 0);
      }
    }
    __syncthreads();
  }

  if (small) {
#pragma unroll
    for (int i = 0; i < 2; ++i)
#pragma unroll
      for (int j = 0; j < 2; ++j)
#pragma unroll
        for (int q = 0; q < 4; ++q) {
          const int row = tileM + w * 32 + i * 16 + (lane >> 4) * 4 + q;
          const int col = j * 16 + (lane & 15);
          const size_t an = (size_t)bz * NN + row;
          float v = accS[i][j][q];
          smallf[an * 32 + col] = v;
          if (col >= 8 && col <= 28) cls_out[an * 21 + (col - 8)] = v;
        }
  } else {
    const int r0 = tileM + wm * 64 + (lane >> 4) * 4;
    const int c0 = bx * 128 + wn * 64 + (lane & 15);
#pragma unroll
    for (int i = 0; i < 4; ++i)
#pragma unroll
      for (int j = 0; j < 4; ++j)
#pragma unroll
        for (int q = 0; q < 4; ++q)
          offb[((size_t)bz * NN + r0 + i * 16 + q) * DAPP + c0 + j * 16] =
              f2b(fmaxf(accM[i][j][q], 0.f));
  }
}

// ================= bf16 GEMM, glds staging, 2-phase dbuf (key path) ================
template<int BM, int BN, int WM, int WN, bool RELU, bool OUTBF, bool SWZ>
__global__ __launch_bounds__(WM * WN * 64)
void gemm_glds(const u16* __restrict__ A, long sA, const u16* __restrict__ B, long sB,
               void* __restrict__ Cv, long sC, int N, int K) {
  constexpr int THREADS = WM * WN * 64;
  constexpr int WTM = BM / WM, WTN = BN / WN;
  constexpr int FM = WTM / 16, FN = WTN / 16;
  constexpr int ACHN = BM * 4, BCHN = BN * 4;
  constexpr int ACH = (ACHN + THREADS - 1) / THREADS;
  constexpr int BCH = (BCHN + THREADS - 1) / THREADS;
  constexpr bool AFULL = (ACHN % THREADS) == 0, BFULL = (BCHN % THREADS) == 0;

  __shared__ __align__(16) u16 As[2][BM * 32];
  __shared__ __align__(16) u16 Bs[2][BN * 32];

  int bx = blockIdx.x, by = blockIdx.y, bz = blockIdx.z;
  if constexpr (SWZ) {
    int gx = gridDim.x, gy = gridDim.y;
    int h = bx + gx * (by + gy * bz);
    int nwg = gx * gy * (int)gridDim.z;
    int cpx = nwg >> 3;
    int l = (h & 7) * cpx + (h >> 3);
    bx = l % gx; l /= gx; by = l % gy; bz = l / gy;
  }

  const int tid = threadIdx.x, lane = tid & 63, wave = tid >> 6;
  const int wm = wave % WM, wn = wave / WM;
  const int tileN = bx * BN, tileM = by * BM;
  const u16* Ab = A + (size_t)bz * sA + (size_t)tileM * K;
  const u16* Bb = B + (size_t)bz * sB + (size_t)tileN * K;

  f32x4 acc[FM][FN];
#pragma unroll
  for (int i = 0; i < FM; ++i)
#pragma unroll
    for (int j = 0; j < FN; ++j) acc[i][j] = (f32x4){0.f, 0.f, 0.f, 0.f};

  auto stage = [&](int buf, int k0) {
#pragma unroll
    for (int i = 0; i < ACH; ++i) {
      int c = tid + i * THREADS;
      if (AFULL || c < ACHN)
        gload_lds16(Ab + (size_t)(c >> 2) * K + k0 + (c & 3) * 8, As[buf] + c * 8);
    }
#pragma unroll
    for (int i = 0; i < BCH; ++i) {
      int c = tid + i * THREADS;
      if (BFULL || c < BCHN)
        gload_lds16(Bb + (size_t)(c >> 2) * K + k0 + (c & 3) * 8, Bs[buf] + c * 8);
    }
  };

  stage(0, 0);
  __syncthreads();
  int cur = 0;
  for (int k0 = 0; k0 < K; k0 += 32) {
    if (k0 + 32 < K) stage(cur ^ 1, k0 + 32);
    const u16* Arow = As[cur] + (wm * WTM + (lane & 15)) * 32 + (lane >> 4) * 8;
    const u16* Brow = Bs[cur] + (wn * WTN + (lane & 15)) * 32 + (lane >> 4) * 8;
    s16x8 af[FM], bfr[FN];
#pragma unroll
    for (int i = 0; i < FM; ++i) af[i] = *(const s16x8*)(Arow + i * 16 * 32);
#pragma unroll
    for (int j = 0; j < FN; ++j) bfr[j] = *(const s16x8*)(Brow + j * 16 * 32);
#pragma unroll
    for (int i = 0; i < FM; ++i)
#pragma unroll
      for (int j = 0; j < FN; ++j)
        acc[i][j] = __builtin_amdgcn_mfma_f32_16x16x32_bf16(af[i], bfr[j], acc[i][j], 0, 0, 0);
    __syncthreads();
    cur ^= 1;
  }

  const int r0 = tileM + wm * WTM + (lane >> 4) * 4;
  const int c0 = tileN + wn * WTN + (lane & 15);
#pragma unroll
  for (int i = 0; i < FM; ++i)
#pragma unroll
    for (int j = 0; j < FN; ++j)
#pragma unroll
      for (int q = 0; q < 4; ++q) {
        float v = acc[i][j][q];
        if (RELU) v = fmaxf(v, 0.f);
        size_t idx = (size_t)bz * sC + (size_t)(r0 + i * 16 + q) * N + (c0 + j * 16);
        if (OUTBF) ((u16*)Cv)[idx] = f2b(v);
        else       ((float*)Cv)[idx] = v;
      }
}

// ================= fallback gemm (A = f32, reg-staged pack) ========================
template<int BM, int BN, int WM, int WN, bool RELU, bool OUTBF>
__global__ __launch_bounds__(WM * WN * 64)
void gemm_af32(const float* __restrict__ Av, const float* __restrict__ A2v, long sA,
               const u16* __restrict__ B, long sB,
               void* __restrict__ Cv, long sC, int N, int K) {
  constexpr int THREADS = WM * WN * 64;
  constexpr int WTM = BM / WM, WTN = BN / WN;
  constexpr int FM = WTM / 16, FN = WTN / 16;
  constexpr int ACH = (BM * 4) / THREADS;
  constexpr int BCHN = BN * 4;
  constexpr int BCH = (BCHN + THREADS - 1) / THREADS;
  constexpr bool BFULL = (BCHN % THREADS) == 0;

  __shared__ __align__(16) u16 As[BM * 32];
  __shared__ __align__(16) u16 Bs[BN * 32];

  const int tid = threadIdx.x, lane = tid & 63, wave = tid >> 6;
  const int wm = wave % WM, wn = wave / WM;
  const int tileN = blockIdx.x * BN, tileM = blockIdx.y * BM;
  const int batch = blockIdx.z;
  const float* base = (batch < 9) ? (Av + (size_t)batch * sA) : A2v;
  const float* Ab32 = base + (size_t)tileM * K;
  const u16* Bb = B + (size_t)batch * sB + (size_t)tileN * K;

  f32x4 acc[FM][FN];
#pragma unroll
  for (int i = 0; i < FM; ++i)
#pragma unroll
    for (int j = 0; j < FN; ++j) acc[i][j] = (f32x4){0.f, 0.f, 0.f, 0.f};

  uint4 ra[ACH], rb[BCH];
  auto load_t = [&](int k0) {
#pragma unroll
    for (int i = 0; i < ACH; ++i) {
      int c = tid + i * THREADS;
      const float* s = Ab32 + (size_t)(c >> 2) * K + k0 + (c & 3) * 8;
      ra[i] = pack8(*(const float4*)s, *(const float4*)(s + 4));
    }
#pragma unroll
    for (int i = 0; i < BCH; ++i) {
      int c = tid + i * THREADS;
      if (BFULL || c < BCHN)
        rb[i] = *(const uint4*)(Bb + (size_t)(c >> 2) * K + k0 + (c & 3) * 8);
    }
  };

  load_t(0);
  const u16* Arow = As + (wm * WTM + (lane & 15)) * 32 + (lane >> 4) * 8;
  const u16* Brow = Bs + (wn * WTN + (lane & 15)) * 32 + (lane >> 4) * 8;

  for (int k0 = 0; k0 < K; k0 += 32) {
    __syncthreads();
#pragma unroll
    for (int i = 0; i < ACH; ++i)
      *(uint4*)(As + (size_t)(tid + i * THREADS) * 8) = ra[i];
#pragma unroll
    for (int i = 0; i < BCH; ++i) {
      int c = tid + i * THREADS;
      if (BFULL || c < BCHN) *(uint4*)(Bs + (size_t)c * 8) = rb[i];
    }
    __syncthreads();
    if (k0 + 32 < K) load_t(k0 + 32);
    s16x8 af[FM], bfr[FN];
#pragma unroll
    for (int i = 0; i < FM; ++i) af[i] = *(const s16x8*)(Arow + i * 16 * 32);
#pragma unroll
    for (int j = 0; j < FN; ++j) bfr[j] = *(const s16x8*)(Brow + j * 16 * 32);
#pragma unroll
    for (int i = 0; i < FM; ++i)
#pragma unroll
      for (int j = 0; j < FN; ++j)
        acc[i][j] = __builtin_amdgcn_mfma_f32_16x16x32_bf16(af[i], bfr[j], acc[i][j], 0, 0, 0);
  }

  const int r0 = tileM + wm * WTM + (lane >> 4) * 4;
  const int c0 = tileN + wn * WTN + (lane & 15);
#pragma unroll
  for (int i = 0; i < FM; ++i)
#pragma unroll
    for (int j = 0; j < FN; ++j)
#pragma unroll
      for (int q = 0; q < 4; ++q) {
        float v = acc[i][j][q];
        if (RELU) v = fmaxf(v, 0.f);
        size_t idx = (size_t)batch * sC + (size_t)(r0 + i * 16 + q) * N + (c0 + j * 16);
        if (OUTBF) ((u16*)Cv)[idx] = f2b(v);
        else       ((float*)Cv)[idx] = v;
      }
}

// ================= cls copy (fallback path only) ===================================
__global__ __launch_bounds__(256) void cls_copy(const float* __restrict__ smallf,
                                                float* __restrict__ o) {
  int i = blockIdx.x * blockDim.x + threadIdx.x;
  if (i >= AN * NN * NCLS) return;
  int an = i / NCLS, c = i % NCLS;
  o[i] = smallf[(size_t)an * 32 + 8 + c];
}

// ================= fused q-projection + beta epilogue, 2-phase dbuf ================
__global__ __launch_bounds__(256) void gemm2qb(const u16* __restrict__ offb,
                                               const u16* __restrict__ Wq,
                                               const float* __restrict__ keyf,
                                               const float* __restrict__ ious,
                                               float* __restrict__ betaf,
                                               float* __restrict__ betac) {
  constexpr int BM = 128, BN = 160;
  __shared__ __align__(16) u16 As[2][BM * 32];
  __shared__ __align__(16) u16 Bs[2][BN * 32];
  const int tid = threadIdx.x, lane = tid & 63, wave = tid >> 6;  // 4 waves on M
  const int tileM = blockIdx.x * BM;
  const int a = blockIdx.y;
  const u16* Ab = offb + ((size_t)a * NN + tileM) * DAPP;
  const u16* Bb = Wq + (size_t)a * QCOLS * DAPP;

  f32x4 acc[2][10];
#pragma unroll
  for (int i = 0; i < 2; ++i)
#pragma unroll
    for (int j = 0; j < 10; ++j) acc[i][j] = (f32x4){0.f, 0.f, 0.f, 0.f};

  auto stage = [&](int buf, int k0) {
#pragma unroll
    for (int i = 0; i < 2; ++i) {          // ACHN = 512
      int c = tid + i * 256;
      gload_lds16(Ab + (size_t)(c >> 2) * DAPP + k0 + (c & 3) * 8, As[buf] + c * 8);
    }
#pragma unroll
    for (int i = 0; i < 3; ++i) {          // BCHN = 640
      int c = tid + i * 256;
      if (c < 640)
        gload_lds16(Bb + (size_t)(c >> 2) * DAPP + k0 + (c & 3) * 8, Bs[buf] + c * 8);
    }
  };

  stage(0, 0);
  __syncthreads();
  int cur = 0;
  for (int k0 = 0; k0 < DAPP; k0 += 32) {
    if (k0 + 32 < DAPP) stage(cur ^ 1, k0 + 32);
    const u16* Arow = As[cur] + (wave * 32 + (lane & 15)) * 32 + (lane >> 4) * 8;
    const u16* Brow = Bs[cur] + (lane & 15) * 32 + (lane >> 4) * 8;
    s16x8 af[2], bfr[10];
#pragma unroll
    for (int i = 0; i < 2; ++i) af[i] = *(const s16x8*)(Arow + i * 16 * 32);
#pragma unroll
    for (int j = 0; j < 10; ++j) bfr[j] = *(const s16x8*)(Brow + j * 16 * 32);
#pragma unroll
    for (int i = 0; i < 2; ++i)
#pragma unroll
      for (int j = 0; j < 10; ++j)
        acc[i][j] = __builtin_amdgcn_mfma_f32_16x16x32_bf16(af[i], bfr[j], acc[i][j], 0, 0, 0);
    __syncthreads();
    cur ^= 1;
  }

  const float scale = 0.17677669529663687f;  // 1/sqrt(32)
  const int cg = lane & 15;
#pragma unroll
  for (int i = 0; i < 2; ++i)
#pragma unroll
    for (int q = 0; q < 4; ++q) {
      const int row = tileM + wave * 32 + i * 16 + (lane >> 4) * 4 + q;
      const float* kr = keyf + (size_t)row * QCOLS;
      float m = 0.f;
#pragma unroll
      for (int j = 0; j < 8; ++j) m += acc[i][j][q] * kr[cg + j * 16];
      float cl = acc[i][8][q] * kr[128 + cg] + acc[i][9][q] * kr[144 + cg];
      m += __shfl_xor(m, 4); m += __shfl_xor(m, 8);
      cl += __shfl_xor(cl, 1); cl += __shfl_xor(cl, 2);
      cl += __shfl_xor(cl, 4); cl += __shfl_xor(cl, 8);
      const float iou = ious[(size_t)a * NN + row];
      if (cg < 4)  betaf[((size_t)a * NN + row) * 4 + (lane & 3)] = m * scale - iou;
      if (cg == 0) betac[(size_t)a * NN + row] = cl * scale - iou;
    }
}

// ================= softmaxes + outputs, thread per (n,c) ===========================
__global__ __launch_bounds__(256) void finalize(const float* __restrict__ smallf,
                                                const float* __restrict__ beta_ws,
                                                const float* __restrict__ betac_ws,
                                                const float* __restrict__ delta_rois,
                                                float* __restrict__ out) {
  int t = blockIdx.x * 256 + threadIdx.x;      // grid = NN*4/256 = 64
  if (t >= NN * 4) return;
  const int n = t >> 2, c = t & 3;

  {
    float al[9], be[9], dp[9];
    float mA = -1e30f, mB = -1e30f;
    for (int a = 0; a < 9; ++a) {
      size_t an = (size_t)a * NN + n;
      al[a] = smallf[an * 32 + c];
      float off_ = smallf[an * 32 + 4 + c];
      dp[a] = delta_rois[an * 5 + 1 + c] + off_;
      be[a] = beta_ws[an * 4 + c];
      mA = fmaxf(mA, al[a]); mB = fmaxf(mB, be[a]);
    }
    float eA[9], eB[9], sA = 0.f, sB = 0.f;
    for (int a = 0; a < 9; ++a) {
      eA[a] = expf(al[a] - mA); sA += eA[a];
      eB[a] = expf(be[a] - mB); sB += eB[a];
    }
    float rA = 1.f / sA, rB = 1.f / sB;
    float ov = 0.f, obv = 0.f;
    for (int a = 0; a < 9; ++a) {
      size_t an = (size_t)a * NN + n;
      float as_ = eA[a] * rA, bs_ = eB[a] * rB;
      out[O2 + an * 4 + c] = as_;
      out[O3 + an * 4 + c] = bs_;
      out[O4 + an * 4 + c] = dp[a];
      out[O5 + an * 4 + c] = dp[a];
      out[O6 + an * 4 + c] = al[a];
      out[O7 + an * 4 + c] = be[a];
      ov += dp[a] * as_; obv += dp[a] * bs_;
    }
    out[O0 + (size_t)n * 4 + c] = ov;
    out[O1 + (size_t)n * 4 + c] = obv;
  }

  if (c == 0) {
    float ac[9], bc[9];
    float mA = -1e30f, mB = -1e30f;
    for (int a = 0; a < 9; ++a) {
      size_t an = (size_t)a * NN + n;
      ac[a] = smallf[an * 32 + 29];
      bc[a] = betac_ws[an];
      mA = fmaxf(mA, ac[a]); mB = fmaxf(mB, bc[a]);
    }
    float eA[9], eB[9], sA = 0.f, sB = 0.f;
    for (int a = 0; a < 9; ++a) {
      eA[a] = expf(ac[a] - mA); sA += eA[a];
      eB[a] = expf(bc[a] - mB); sB += eB[a];
    }
    float rA = 1.f / sA, rB = 1.f / sB;
    for (int a = 0; a < 9; ++a) {
      size_t an = (size_t)a * NN + n;
      out[O9 + an]  = eA[a] * rA;
      out[O10 + an] = eB[a] * rB;
      out[O11 + an] = ac[a];
      out[O12 + an] = bc[a];
    }
  }
}

extern "C" void kernel_launch(void* const* d_in, const int* in_sizes, int n_in,
                              void* d_out, int out_size, void* d_ws, size_t ws_size,
                              hipStream_t stream) {
  const float* delta_rois = (const float*)d_in[1];
  const float* features   = (const float*)d_in[2];
  const float* gt_features= (const float*)d_in[3];
  const float* ious       = (const float*)d_in[4];
  const float* att        = (const float*)d_in[5];
  const float* w_k        = (const float*)d_in[6];
  const float* w_q        = (const float*)d_in[7];
  const float* alpha_w    = (const float*)d_in[8];
  const float* bbox       = (const float*)d_in[9];
  const float* w_k_cls    = (const float*)d_in[10];
  const float* w_q_cls    = (const float*)d_in[11];
  const float* alpha_w_cls= (const float*)d_in[12];
  const float* cls_w      = (const float*)d_in[13];
  float* out = (float*)d_out;

  char* ws = (char*)d_ws;
  u16* attB    = (u16*)ws;   ws += (size_t)DAPP * DORI * 2;       // 2.1 MB
  u16* Wq      = (u16*)ws;   ws += (size_t)NB * QCOLS * DAPP * 2; // 1.6 MB
  u16* Wsmall  = (u16*)ws;   ws += (size_t)AN * 32 * DORI * 2;    // 1.2 MB
  u16* offb    = (u16*)ws;   ws += (size_t)NB * NN * DAPP * 2;    // 42 MB (batch9 = gt_off)
  float* smallf= (float*)ws; ws += (size_t)AN * NN * 32 * 4;      // 4.7 MB
  float* keyf  = (float*)ws; ws += (size_t)NN * QCOLS * 4;        // 2.6 MB
  float* betaf = (float*)ws; ws += (size_t)AN * NN * 4 * 4;       // 2.4 MB
  float* betac = (float*)ws; ws += (size_t)AN * NN * 4;           // 0.15 MB
  size_t base_bytes = (size_t)(ws - (char*)d_ws);
  size_t featB_bytes = (size_t)NB * NN * DORI * 2;                // 168 MB
  bool big = ws_size >= base_bytes + featB_bytes;
  u16* featB = big ? (u16*)ws : nullptr;

  // 1. fused prep + full-feature cast (one launch)
  prep_cast<<<PREP_TOTAL, 256, 0, stream>>>(features, att, w_q, w_q_cls, w_k, w_k_cls,
                                            alpha_w, bbox, alpha_w_cls, cls_w,
                                            gt_features, featB, attB, Wq, Wsmall);

  if (big) {
    // 2. off + smallf + cls: BM=256, BK=64, panel-local XCD swizzle
    dim3 gm(5, 16, NB);
    gemm_main<<<gm, 512, 0, stream>>>(featB, attB, Wsmall, offb, smallf, out + O8);
  } else {
    dim3 g1(DAPP / 128, NN / 128, NB);
    gemm_af32<128, 128, 2, 2, true, true><<<g1, 256, 0, stream>>>(
        features, gt_features, (long)NN * DORI, attB, 0, offb, (long)NN * DAPP, DAPP, DORI);
    dim3 gsm(1, NN / 128, AN);
    gemm_af32<128, 32, 4, 1, false, false><<<gsm, 256, 0, stream>>>(
        features, nullptr, (long)NN * DORI, Wsmall, (long)32 * DORI,
        smallf, (long)NN * 32, 32, DORI);
    cls_copy<<<(AN * NN * NCLS + 255) / 256, 256, 0, stream>>>(smallf, out + O8);
  }

  // 3. key = gt_off @ Wq[9]^T (batch 9) -> keyf f32
  dim3 gk(QCOLS / 32, NN / 128, 1);
  gemm_glds<128, 32, 4, 1, false, false, false><<<gk, 256, 0, stream>>>(
      offb + (size_t)9 * NN * DAPP, 0, Wq + (size_t)9 * QCOLS * DAPP, 0,
      keyf, 0, QCOLS, DAPP);

  // 4. fused q-projection + beta (batches 0-8)
  dim3 g2(NN / 128, AN, 1);
  gemm2qb<<<g2, 256, 0, stream>>>(offb, Wq, keyf, ious, betaf, betac);

  // 5. softmaxes + outputs
  finalize<<<NN * 4 / 256, 256, 0, stream>>>(smallf, betaf, betac, delta_rois, out);
}

// Round 15
// 295.412 us; speedup vs baseline: 1.0102x; 1.0102x over previous
//
#include <hip/hip_runtime.h>

using u16 = unsigned short;
using s16x8 = __attribute__((ext_vector_type(8))) short;   // 8 bf16 (4 VGPRs)
using f32x4 = __attribute__((ext_vector_type(4))) float;

#define DEVI __device__ __forceinline__

constexpr int AN = 9, NB = 10, NN = 4096, DORI = 2048, DAPP = 512, NCLS = 21, QCOLS = 160;

// output offsets (f32 elements) in return order
constexpr size_t O0 = 0;                 // output            (4096,4)
constexpr size_t O1 = 16384;             // output_beta       (4096,4)
constexpr size_t O2 = 32768;             // alpha_softmax     (9,4096,4)
constexpr size_t O3 = 180224;            // beta_softmax      (9,4096,4)
constexpr size_t O4 = 327680;            // delta_pred_offset (9,4096,4)
constexpr size_t O5 = 475136;            // delta_pred_offset (9,4096,4)
constexpr size_t O6 = 622592;            // alpha             (9,4096,4)
constexpr size_t O7 = 770048;            // beta_out          (9,4096,4)
constexpr size_t O8 = 917504;            // cls_score         (9,4096,21)
constexpr size_t O9 = 1691648;           // alpha_softmax_cls (9,4096,1)
constexpr size_t O10 = 1728512;          // beta_softmax_cls
constexpr size_t O11 = 1765376;          // alpha_cls
constexpr size_t O12 = 1802240;          // beta_out_cls

// prep_cast block ranges
constexpr int CAST_B = 36864;            // AN*NN*DORI/8/256
constexpr int ATT_B  = 256;              // (2048/64)*(512/64)
constexpr int PQ_B   = 3200;             // NB*QCOLS*DAPP/256
constexpr int PS_B   = 72;               // AN*DORI/256
constexpr int GT_B   = 4096;             // NN*DORI/8/256
constexpr int PREP_TOTAL = CAST_B + ATT_B + PQ_B + PS_B + GT_B;   // 44488

DEVI u16 f2b(float f) {                   // f32 -> bf16 RNE (internal use only)
  unsigned u = __float_as_uint(f);
  unsigned r = (u + 0x7fffu + ((u >> 16) & 1u)) >> 16;
  return (u16)r;
}

DEVI uint4 pack8(float4 u, float4 v) {    // 8 f32 -> 8 bf16 packed
  uint4 r;
  r.x = (unsigned)f2b(u.x) | ((unsigned)f2b(u.y) << 16);
  r.y = (unsigned)f2b(u.z) | ((unsigned)f2b(u.w) << 16);
  r.z = (unsigned)f2b(v.x) | ((unsigned)f2b(v.y) << 16);
  r.w = (unsigned)f2b(v.z) | ((unsigned)f2b(v.w) << 16);
  return r;
}

DEVI void gload_lds16(const u16* g, u16* l) {   // 16B global -> LDS direct
  __builtin_amdgcn_global_load_lds(
      (const __attribute__((address_space(1))) void*)g,
      (__attribute__((address_space(3))) void*)l, 16, 0, 0);
}

// ================= prep_cast: cast | att-transpose | pack_q | pack_small | gt ======
__global__ __launch_bounds__(256) void prep_cast(const float* __restrict__ features,
                                                 const float* __restrict__ att,
                                                 const float* __restrict__ wq,
                                                 const float* __restrict__ wqc,
                                                 const float* __restrict__ wk,
                                                 const float* __restrict__ wkc,
                                                 const float* __restrict__ aw,
                                                 const float* __restrict__ bb,
                                                 const float* __restrict__ awc,
                                                 const float* __restrict__ cw,
                                                 const float* __restrict__ gt,
                                                 u16* __restrict__ featB,
                                                 u16* __restrict__ attB,
                                                 u16* __restrict__ Wq,
                                                 u16* __restrict__ Wsm) {
  __shared__ float tile[64][65];
  const int b = blockIdx.x, tid = threadIdx.x;
  if (b < CAST_B) {                                 // features f32 -> featB[0..8]
    if (!featB) return;
    long i = (long)b * 256 + tid;
    float4 v0 = ((const float4*)features)[i * 2];
    float4 v1 = ((const float4*)features)[i * 2 + 1];
    ((uint4*)featB)[i] = pack8(v0, v1);
  } else if (b < CAST_B + ATT_B) {                  // attB[c][d] = att[d][c], LDS tile
    int b2 = b - CAST_B;
    int d0 = (b2 >> 3) * 64, c0 = (b2 & 7) * 64;
#pragma unroll
    for (int r = 0; r < 16; ++r) {
      int dl = r * 4 + (tid >> 6), cl = tid & 63;
      tile[dl][cl] = att[(size_t)(d0 + dl) * DAPP + c0 + cl];
    }
    __syncthreads();
#pragma unroll
    for (int w = 0; w < 16; ++w) {
      int cl = w * 4 + (tid >> 6), dl = tid & 63;
      attB[(size_t)(c0 + cl) * DORI + d0 + dl] = f2b(tile[dl][cl]);
    }
  } else if (b < CAST_B + ATT_B + PQ_B) {           // Wq[b][160][512]
    int t = (b - CAST_B - ATT_B) * 256 + tid;
    int bq = t / (QCOLS * DAPP);
    int r = t % (QCOLS * DAPP);
    int col = r / DAPP, d = r % DAPP;
    float v;
    if (bq < 9) {
      if (col < 128) v = wq[(size_t)bq * DAPP * 128 + (size_t)d * 128 + col];
      else           v = wqc[(size_t)bq * DAPP * 32 + (size_t)d * 32 + (col - 128)];
    } else {
      if (col < 128) v = wk[(size_t)d * 128 + col];
      else           v = wkc[(size_t)d * 32 + (col - 128)];
    }
    Wq[t] = f2b(v);
  } else if (b < CAST_B + ATT_B + PQ_B + PS_B) {    // Wsmall[a][32][2048]
    int t = (b - CAST_B - ATT_B - PQ_B) * 256 + tid;
    if (t >= AN * DORI) return;
    int a = t / DORI, f = t % DORI;
    u16* Wa = Wsm + (size_t)a * 32 * DORI;
    for (int c = 0; c < 4; ++c)  Wa[c * DORI + f]       = f2b(aw[((size_t)a * DORI + f) * 4 + c]);
    for (int c = 0; c < 4; ++c)  Wa[(4 + c) * DORI + f] = f2b(bb[((size_t)a * DORI + f) * 4 + c]);
    for (int c = 0; c < 21; ++c) Wa[(8 + c) * DORI + f] = f2b(cw[((size_t)a * DORI + f) * 21 + c]);
    Wa[29 * DORI + f] = f2b(awc[(size_t)a * DORI + f]);
    Wa[30 * DORI + f] = 0;
    Wa[31 * DORI + f] = 0;
  } else {                                          // gt_features -> featB[9]
    if (!featB) return;
    long i = (long)(b - CAST_B - ATT_B - PQ_B - PS_B) * 256 + tid;
    float4 v0 = ((const float4*)gt)[i * 2];
    float4 v1 = ((const float4*)gt)[i * 2 + 1];
    ((uint4*)(featB + (size_t)AN * NN * DORI))[i] = pack8(v0, v1);
  }
}

// ================= gemm_main: 128x128(+small), BK=64, swizzled, 1 barrier pair/64k ==
// grid (5, 32, 10), 256 threads; bx<4: off 128x128 (wave 64x64), bx==4: smallf
// 128x32 (wave 32x32). LDS [row][64]: physical chunk p holds logical kc = p^(row&7)
// (stage pre-swizzles the GLOBAL col; LDS dest linear; reads XOR same involution).
// 32 MFMA per wave per barrier pair. ROUND-13 CONFIG == session best (294 us);
// BM=256 (r14) and all schedule variants (r9-r11) measured equal or worse.
__global__ __launch_bounds__(256) void gemm_main(const u16* __restrict__ featB,
                                                 const u16* __restrict__ attB,
                                                 const u16* __restrict__ Wsm,
                                                 u16* __restrict__ offb,
                                                 float* __restrict__ smallf,
                                                 float* __restrict__ cls_out) {
  __shared__ __align__(16) u16 As[128 * 64];   // 16 KB
  __shared__ __align__(16) u16 Bs[128 * 64];   // 16 KB

  int bx = blockIdx.x, by = blockIdx.y, bz = blockIdx.z;
  {                                   // nwg = 1600, cpx = 200
    int h = bx + 5 * (by + 32 * bz);
    int l = (h & 7) * 200 + (h >> 3);
    bx = l % 5; l /= 5; by = l % 32; bz = l / 32;
  }
  const int tid = threadIdx.x, lane = tid & 63, w = tid >> 6;
  const bool small = (bx == 4);
  if (small && bz == 9) return;       // no small path for gt batch
  const int tileM = by * 128;
  const u16* Ab = featB + ((size_t)bz * NN + tileM) * DORI;
  const u16* Bb = small ? (Wsm + (size_t)bz * 32 * DORI)
                        : (attB + (size_t)bx * 128 * DORI);

  f32x4 accM[4][4], accS[2][2];
#pragma unroll
  for (int i = 0; i < 4; ++i)
#pragma unroll
    for (int j = 0; j < 4; ++j) accM[i][j] = (f32x4){0.f, 0.f, 0.f, 0.f};
#pragma unroll
  for (int i = 0; i < 2; ++i)
#pragma unroll
    for (int j = 0; j < 2; ++j) accS[i][j] = (f32x4){0.f, 0.f, 0.f, 0.f};

  const int wm = w & 1, wn = w >> 1;

  // stage swizzle: chunk c -> row = c>>3, phys = c&7, logical kc = phys ^ (row&7)
  int arow[4], acol[4];
#pragma unroll
  for (int i = 0; i < 4; ++i) {
    int c = tid + i * 256;
    arow[i] = c >> 3;
    acol[i] = (((c & 7) ^ ((c >> 3) & 7))) * 8;
  }
  // read swizzle: row&7 = lane&7 (row = 16*b + (lane&15));
  // logical chunk lc = mk*4 + (lane>>4); phys = lc ^ (lane&7)
  const int lanerow = (lane & 15) * 64;
  const int ph0 = (((lane >> 4)) ^ (lane & 7)) * 8;        // mk = 0
  const int ph1 = (((lane >> 4) + 4) ^ (lane & 7)) * 8;    // mk = 1

  for (int k0 = 0; k0 < DORI; k0 += 64) {
#pragma unroll
    for (int i = 0; i < 4; ++i)
      gload_lds16(Ab + (size_t)arow[i] * DORI + k0 + acol[i], As + (tid + i * 256) * 8);
    if (small) {
      // B: 32 rows x 8 chunks = 256 chunks, one per thread
      gload_lds16(Bb + (size_t)(tid >> 3) * DORI + k0 + (((tid & 7) ^ ((tid >> 3) & 7)) * 8),
                  Bs + tid * 8);
    } else {
#pragma unroll
      for (int i = 0; i < 4; ++i)
        gload_lds16(Bb + (size_t)arow[i] * DORI + k0 + acol[i], Bs + (tid + i * 256) * 8);
    }
    __syncthreads();
    if (small) {
#pragma unroll
      for (int mk = 0; mk < 2; ++mk) {
        const int ph = mk ? ph1 : ph0;
        s16x8 af[2], bf[2];
#pragma unroll
        for (int i = 0; i < 2; ++i)
          af[i] = *(const s16x8*)(As + (w * 32 + i * 16) * 64 + lanerow + ph);
#pragma unroll
        for (int j = 0; j < 2; ++j)
          bf[j] = *(const s16x8*)(Bs + (j * 16) * 64 + lanerow + ph);
#pragma unroll
        for (int i = 0; i < 2; ++i)
#pragma unroll
          for (int j = 0; j < 2; ++j)
            accS[i][j] = __builtin_amdgcn_mfma_f32_16x16x32_bf16(af[i], bf[j], accS[i][j], 0, 0, 0);
      }
    } else {
#pragma unroll
      for (int mk = 0; mk < 2; ++mk) {
        const int ph = mk ? ph1 : ph0;
        s16x8 af[4], bf[4];
#pragma unroll
        for (int i = 0; i < 4; ++i)
          af[i] = *(const s16x8*)(As + (wm * 64 + i * 16) * 64 + lanerow + ph);
#pragma unroll
        for (int j = 0; j < 4; ++j)
          bf[j] = *(const s16x8*)(Bs + (wn * 64 + j * 16) * 64 + lanerow + ph);
#pragma unroll
        for (int i = 0; i < 4; ++i)
#pragma unroll
          for (int j = 0; j < 4; ++j)
            accM[i][j] = __builtin_amdgcn_mfma_f32_16x16x32_bf16(af[i], bf[j], accM[i][j], 0, 0, 0);
      }
    }
    __syncthreads();
  }

  if (small) {
#pragma unroll
    for (int i = 0; i < 2; ++i)
#pragma unroll
      for (int j = 0; j < 2; ++j)
#pragma unroll
        for (int q = 0; q < 4; ++q) {
          const int row = tileM + w * 32 + i * 16 + (lane >> 4) * 4 + q;
          const int col = j * 16 + (lane & 15);
          const size_t an = (size_t)bz * NN + row;
          float v = accS[i][j][q];
          smallf[an * 32 + col] = v;
          if (col >= 8 && col <= 28) cls_out[an * 21 + (col - 8)] = v;
        }
  } else {
    const int r0 = tileM + wm * 64 + (lane >> 4) * 4;
    const int c0 = bx * 128 + wn * 64 + (lane & 15);
#pragma unroll
    for (int i = 0; i < 4; ++i)
#pragma unroll
      for (int j = 0; j < 4; ++j)
#pragma unroll
        for (int q = 0; q < 4; ++q)
          offb[((size_t)bz * NN + r0 + i * 16 + q) * DAPP + c0 + j * 16] =
              f2b(fmaxf(accM[i][j][q], 0.f));
  }
}

// ================= bf16 GEMM, glds staging, 2-phase dbuf (key path) ================
template<int BM, int BN, int WM, int WN, bool RELU, bool OUTBF, bool SWZ>
__global__ __launch_bounds__(WM * WN * 64)
void gemm_glds(const u16* __restrict__ A, long sA, const u16* __restrict__ B, long sB,
               void* __restrict__ Cv, long sC, int N, int K) {
  constexpr int THREADS = WM * WN * 64;
  constexpr int WTM = BM / WM, WTN = BN / WN;
  constexpr int FM = WTM / 16, FN = WTN / 16;
  constexpr int ACHN = BM * 4, BCHN = BN * 4;
  constexpr int ACH = (ACHN + THREADS - 1) / THREADS;
  constexpr int BCH = (BCHN + THREADS - 1) / THREADS;
  constexpr bool AFULL = (ACHN % THREADS) == 0, BFULL = (BCHN % THREADS) == 0;

  __shared__ __align__(16) u16 As[2][BM * 32];
  __shared__ __align__(16) u16 Bs[2][BN * 32];

  int bx = blockIdx.x, by = blockIdx.y, bz = blockIdx.z;
  if constexpr (SWZ) {
    int gx = gridDim.x, gy = gridDim.y;
    int h = bx + gx * (by + gy * bz);
    int nwg = gx * gy * (int)gridDim.z;
    int cpx = nwg >> 3;
    int l = (h & 7) * cpx + (h >> 3);
    bx = l % gx; l /= gx; by = l % gy; bz = l / gy;
  }

  const int tid = threadIdx.x, lane = tid & 63, wave = tid >> 6;
  const int wm = wave % WM, wn = wave / WM;
  const int tileN = bx * BN, tileM = by * BM;
  const u16* Ab = A + (size_t)bz * sA + (size_t)tileM * K;
  const u16* Bb = B + (size_t)bz * sB + (size_t)tileN * K;

  f32x4 acc[FM][FN];
#pragma unroll
  for (int i = 0; i < FM; ++i)
#pragma unroll
    for (int j = 0; j < FN; ++j) acc[i][j] = (f32x4){0.f, 0.f, 0.f, 0.f};

  auto stage = [&](int buf, int k0) {
#pragma unroll
    for (int i = 0; i < ACH; ++i) {
      int c = tid + i * THREADS;
      if (AFULL || c < ACHN)
        gload_lds16(Ab + (size_t)(c >> 2) * K + k0 + (c & 3) * 8, As[buf] + c * 8);
    }
#pragma unroll
    for (int i = 0; i < BCH; ++i) {
      int c = tid + i * THREADS;
      if (BFULL || c < BCHN)
        gload_lds16(Bb + (size_t)(c >> 2) * K + k0 + (c & 3) * 8, Bs[buf] + c * 8);
    }
  };

  stage(0, 0);
  __syncthreads();
  int cur = 0;
  for (int k0 = 0; k0 < K; k0 += 32) {
    if (k0 + 32 < K) stage(cur ^ 1, k0 + 32);
    const u16* Arow = As[cur] + (wm * WTM + (lane & 15)) * 32 + (lane >> 4) * 8;
    const u16* Brow = Bs[cur] + (wn * WTN + (lane & 15)) * 32 + (lane >> 4) * 8;
    s16x8 af[FM], bfr[FN];
#pragma unroll
    for (int i = 0; i < FM; ++i) af[i] = *(const s16x8*)(Arow + i * 16 * 32);
#pragma unroll
    for (int j = 0; j < FN; ++j) bfr[j] = *(const s16x8*)(Brow + j * 16 * 32);
#pragma unroll
    for (int i = 0; i < FM; ++i)
#pragma unroll
      for (int j = 0; j < FN; ++j)
        acc[i][j] = __builtin_amdgcn_mfma_f32_16x16x32_bf16(af[i], bfr[j], acc[i][j], 0, 0, 0);
    __syncthreads();
    cur ^= 1;
  }

  const int r0 = tileM + wm * WTM + (lane >> 4) * 4;
  const int c0 = tileN + wn * WTN + (lane & 15);
#pragma unroll
  for (int i = 0; i < FM; ++i)
#pragma unroll
    for (int j = 0; j < FN; ++j)
#pragma unroll
      for (int q = 0; q < 4; ++q) {
        float v = acc[i][j][q];
        if (RELU) v = fmaxf(v, 0.f);
        size_t idx = (size_t)bz * sC + (size_t)(r0 + i * 16 + q) * N + (c0 + j * 16);
        if (OUTBF) ((u16*)Cv)[idx] = f2b(v);
        else       ((float*)Cv)[idx] = v;
      }
}

// ================= fallback gemm (A = f32, reg-staged pack) ========================
template<int BM, int BN, int WM, int WN, bool RELU, bool OUTBF>
__global__ __launch_bounds__(WM * WN * 64)
void gemm_af32(const float* __restrict__ Av, const float* __restrict__ A2v, long sA,
               const u16* __restrict__ B, long sB,
               void* __restrict__ Cv, long sC, int N, int K) {
  constexpr int THREADS = WM * WN * 64;
  constexpr int WTM = BM / WM, WTN = BN / WN;
  constexpr int FM = WTM / 16, FN = WTN / 16;
  constexpr int ACH = (BM * 4) / THREADS;
  constexpr int BCHN = BN * 4;
  constexpr int BCH = (BCHN + THREADS - 1) / THREADS;
  constexpr bool BFULL = (BCHN % THREADS) == 0;

  __shared__ __align__(16) u16 As[BM * 32];
  __shared__ __align__(16) u16 Bs[BN * 32];

  const int tid = threadIdx.x, lane = tid & 63, wave = tid >> 6;
  const int wm = wave % WM, wn = wave / WM;
  const int tileN = blockIdx.x * BN, tileM = blockIdx.y * BM;
  const int batch = blockIdx.z;
  const float* base = (batch < 9) ? (Av + (size_t)batch * sA) : A2v;
  const float* Ab32 = base + (size_t)tileM * K;
  const u16* Bb = B + (size_t)batch * sB + (size_t)tileN * K;

  f32x4 acc[FM][FN];
#pragma unroll
  for (int i = 0; i < FM; ++i)
#pragma unroll
    for (int j = 0; j < FN; ++j) acc[i][j] = (f32x4){0.f, 0.f, 0.f, 0.f};

  uint4 ra[ACH], rb[BCH];
  auto load_t = [&](int k0) {
#pragma unroll
    for (int i = 0; i < ACH; ++i) {
      int c = tid + i * THREADS;
      const float* s = Ab32 + (size_t)(c >> 2) * K + k0 + (c & 3) * 8;
      ra[i] = pack8(*(const float4*)s, *(const float4*)(s + 4));
    }
#pragma unroll
    for (int i = 0; i < BCH; ++i) {
      int c = tid + i * THREADS;
      if (BFULL || c < BCHN)
        rb[i] = *(const uint4*)(Bb + (size_t)(c >> 2) * K + k0 + (c & 3) * 8);
    }
  };

  load_t(0);
  const u16* Arow = As + (wm * WTM + (lane & 15)) * 32 + (lane >> 4) * 8;
  const u16* Brow = Bs + (wn * WTN + (lane & 15)) * 32 + (lane >> 4) * 8;

  for (int k0 = 0; k0 < K; k0 += 32) {
    __syncthreads();
#pragma unroll
    for (int i = 0; i < ACH; ++i)
      *(uint4*)(As + (size_t)(tid + i * THREADS) * 8) = ra[i];
#pragma unroll
    for (int i = 0; i < BCH; ++i) {
      int c = tid + i * THREADS;
      if (BFULL || c < BCHN) *(uint4*)(Bs + (size_t)c * 8) = rb[i];
    }
    __syncthreads();
    if (k0 + 32 < K) load_t(k0 + 32);
    s16x8 af[FM], bfr[FN];
#pragma unroll
    for (int i = 0; i < FM; ++i) af[i] = *(const s16x8*)(Arow + i * 16 * 32);
#pragma unroll
    for (int j = 0; j < FN; ++j) bfr[j] = *(const s16x8*)(Brow + j * 16 * 32);
#pragma unroll
    for (int i = 0; i < FM; ++i)
#pragma unroll
      for (int j = 0; j < FN; ++j)
        acc[i][j] = __builtin_amdgcn_mfma_f32_16x16x32_bf16(af[i], bfr[j], acc[i][j], 0, 0, 0);
  }

  const int r0 = tileM + wm * WTM + (lane >> 4) * 4;
  const int c0 = tileN + wn * WTN + (lane & 15);
#pragma unroll
  for (int i = 0; i < FM; ++i)
#pragma unroll
    for (int j = 0; j < FN; ++j)
#pragma unroll
      for (int q = 0; q < 4; ++q) {
        float v = acc[i][j][q];
        if (RELU) v = fmaxf(v, 0.f);
        size_t idx = (size_t)batch * sC + (size_t)(r0 + i * 16 + q) * N + (c0 + j * 16);
        if (OUTBF) ((u16*)Cv)[idx] = f2b(v);
        else       ((float*)Cv)[idx] = v;
      }
}

// ================= cls copy (fallback path only) ===================================
__global__ __launch_bounds__(256) void cls_copy(const float* __restrict__ smallf,
                                                float* __restrict__ o) {
  int i = blockIdx.x * blockDim.x + threadIdx.x;
  if (i >= AN * NN * NCLS) return;
  int an = i / NCLS, c = i % NCLS;
  o[i] = smallf[(size_t)an * 32 + 8 + c];
}

// ================= fused q-projection + beta epilogue, 2-phase dbuf ================
__global__ __launch_bounds__(256) void gemm2qb(const u16* __restrict__ offb,
                                               const u16* __restrict__ Wq,
                                               const float* __restrict__ keyf,
                                               const float* __restrict__ ious,
                                               float* __restrict__ betaf,
                                               float* __restrict__ betac) {
  constexpr int BM = 128, BN = 160;
  __shared__ __align__(16) u16 As[2][BM * 32];
  __shared__ __align__(16) u16 Bs[2][BN * 32];
  const int tid = threadIdx.x, lane = tid & 63, wave = tid >> 6;  // 4 waves on M
  const int tileM = blockIdx.x * BM;
  const int a = blockIdx.y;
  const u16* Ab = offb + ((size_t)a * NN + tileM) * DAPP;
  const u16* Bb = Wq + (size_t)a * QCOLS * DAPP;

  f32x4 acc[2][10];
#pragma unroll
  for (int i = 0; i < 2; ++i)
#pragma unroll
    for (int j = 0; j < 10; ++j) acc[i][j] = (f32x4){0.f, 0.f, 0.f, 0.f};

  auto stage = [&](int buf, int k0) {
#pragma unroll
    for (int i = 0; i < 2; ++i) {          // ACHN = 512
      int c = tid + i * 256;
      gload_lds16(Ab + (size_t)(c >> 2) * DAPP + k0 + (c & 3) * 8, As[buf] + c * 8);
    }
#pragma unroll
    for (int i = 0; i < 3; ++i) {          // BCHN = 640
      int c = tid + i * 256;
      if (c < 640)
        gload_lds16(Bb + (size_t)(c >> 2) * DAPP + k0 + (c & 3) * 8, Bs[buf] + c * 8);
    }
  };

  stage(0, 0);
  __syncthreads();
  int cur = 0;
  for (int k0 = 0; k0 < DAPP; k0 += 32) {
    if (k0 + 32 < DAPP) stage(cur ^ 1, k0 + 32);
    const u16* Arow = As[cur] + (wave * 32 + (lane & 15)) * 32 + (lane >> 4) * 8;
    const u16* Brow = Bs[cur] + (lane & 15) * 32 + (lane >> 4) * 8;
    s16x8 af[2], bfr[10];
#pragma unroll
    for (int i = 0; i < 2; ++i) af[i] = *(const s16x8*)(Arow + i * 16 * 32);
#pragma unroll
    for (int j = 0; j < 10; ++j) bfr[j] = *(const s16x8*)(Brow + j * 16 * 32);
#pragma unroll
    for (int i = 0; i < 2; ++i)
#pragma unroll
      for (int j = 0; j < 10; ++j)
        acc[i][j] = __builtin_amdgcn_mfma_f32_16x16x32_bf16(af[i], bfr[j], acc[i][j], 0, 0, 0);
    __syncthreads();
    cur ^= 1;
  }

  const float scale = 0.17677669529663687f;  // 1/sqrt(32)
  const int cg = lane & 15;
#pragma unroll
  for (int i = 0; i < 2; ++i)
#pragma unroll
    for (int q = 0; q < 4; ++q) {
      const int row = tileM + wave * 32 + i * 16 + (lane >> 4) * 4 + q;
      const float* kr = keyf + (size_t)row * QCOLS;
      float m = 0.f;
#pragma unroll
      for (int j = 0; j < 8; ++j) m += acc[i][j][q] * kr[cg + j * 16];
      float cl = acc[i][8][q] * kr[128 + cg] + acc[i][9][q] * kr[144 + cg];
      m += __shfl_xor(m, 4); m += __shfl_xor(m, 8);
      cl += __shfl_xor(cl, 1); cl += __shfl_xor(cl, 2);
      cl += __shfl_xor(cl, 4); cl += __shfl_xor(cl, 8);
      const float iou = ious[(size_t)a * NN + row];
      if (cg < 4)  betaf[((size_t)a * NN + row) * 4 + (lane & 3)] = m * scale - iou;
      if (cg == 0) betac[(size_t)a * NN + row] = cl * scale - iou;
    }
}

// ================= softmaxes + outputs, thread per (n,c) ===========================
__global__ __launch_bounds__(256) void finalize(const float* __restrict__ smallf,
                                                const float* __restrict__ beta_ws,
                                                const float* __restrict__ betac_ws,
                                                const float* __restrict__ delta_rois,
                                                float* __restrict__ out) {
  int t = blockIdx.x * 256 + threadIdx.x;      // grid = NN*4/256 = 64
  if (t >= NN * 4) return;
  const int n = t >> 2, c = t & 3;

  {
    float al[9], be[9], dp[9];
    float mA = -1e30f, mB = -1e30f;
    for (int a = 0; a < 9; ++a) {
      size_t an = (size_t)a * NN + n;
      al[a] = smallf[an * 32 + c];
      float off_ = smallf[an * 32 + 4 + c];
      dp[a] = delta_rois[an * 5 + 1 + c] + off_;
      be[a] = beta_ws[an * 4 + c];
      mA = fmaxf(mA, al[a]); mB = fmaxf(mB, be[a]);
    }
    float eA[9], eB[9], sA = 0.f, sB = 0.f;
    for (int a = 0; a < 9; ++a) {
      eA[a] = expf(al[a] - mA); sA += eA[a];
      eB[a] = expf(be[a] - mB); sB += eB[a];
    }
    float rA = 1.f / sA, rB = 1.f / sB;
    float ov = 0.f, obv = 0.f;
    for (int a = 0; a < 9; ++a) {
      size_t an = (size_t)a * NN + n;
      float as_ = eA[a] * rA, bs_ = eB[a] * rB;
      out[O2 + an * 4 + c] = as_;
      out[O3 + an * 4 + c] = bs_;
      out[O4 + an * 4 + c] = dp[a];
      out[O5 + an * 4 + c] = dp[a];
      out[O6 + an * 4 + c] = al[a];
      out[O7 + an * 4 + c] = be[a];
      ov += dp[a] * as_; obv += dp[a] * bs_;
    }
    out[O0 + (size_t)n * 4 + c] = ov;
    out[O1 + (size_t)n * 4 + c] = obv;
  }

  if (c == 0) {
    float ac[9], bc[9];
    float mA = -1e30f, mB = -1e30f;
    for (int a = 0; a < 9; ++a) {
      size_t an = (size_t)a * NN + n;
      ac[a] = smallf[an * 32 + 29];
      bc[a] = betac_ws[an];
      mA = fmaxf(mA, ac[a]); mB = fmaxf(mB, bc[a]);
    }
    float eA[9], eB[9], sA = 0.f, sB = 0.f;
    for (int a = 0; a < 9; ++a) {
      eA[a] = expf(ac[a] - mA); sA += eA[a];
      eB[a] = expf(bc[a] - mB); sB += eB[a];
    }
    float rA = 1.f / sA, rB = 1.f / sB;
    for (int a = 0; a < 9; ++a) {
      size_t an = (size_t)a * NN + n;
      out[O9 + an]  = eA[a] * rA;
      out[O10 + an] = eB[a] * rB;
      out[O11 + an] = ac[a];
      out[O12 + an] = bc[a];
    }
  }
}

extern "C" void kernel_launch(void* const* d_in, const int* in_sizes, int n_in,
                              void* d_out, int out_size, void* d_ws, size_t ws_size,
                              hipStream_t stream) {
  const float* delta_rois = (const float*)d_in[1];
  const float* features   = (const float*)d_in[2];
  const float* gt_features= (const float*)d_in[3];
  const float* ious       = (const float*)d_in[4];
  const float* att        = (const float*)d_in[5];
  const float* w_k        = (const float*)d_in[6];
  const float* w_q        = (const float*)d_in[7];
  const float* alpha_w    = (const float*)d_in[8];
  const float* bbox       = (const float*)d_in[9];
  const float* w_k_cls    = (const float*)d_in[10];
  const float* w_q_cls    = (const float*)d_in[11];
  const float* alpha_w_cls= (const float*)d_in[12];
  const float* cls_w      = (const float*)d_in[13];
  float* out = (float*)d_out;

  char* ws = (char*)d_ws;
  u16* attB    = (u16*)ws;   ws += (size_t)DAPP * DORI * 2;       // 2.1 MB
  u16* Wq      = (u16*)ws;   ws += (size_t)NB * QCOLS * DAPP * 2; // 1.6 MB
  u16* Wsmall  = (u16*)ws;   ws += (size_t)AN * 32 * DORI * 2;    // 1.2 MB
  u16* offb    = (u16*)ws;   ws += (size_t)NB * NN * DAPP * 2;    // 42 MB (batch9 = gt_off)
  float* smallf= (float*)ws; ws += (size_t)AN * NN * 32 * 4;      // 4.7 MB
  float* keyf  = (float*)ws; ws += (size_t)NN * QCOLS * 4;        // 2.6 MB
  float* betaf = (float*)ws; ws += (size_t)AN * NN * 4 * 4;       // 2.4 MB
  float* betac = (float*)ws; ws += (size_t)AN * NN * 4;           // 0.15 MB
  size_t base_bytes = (size_t)(ws - (char*)d_ws);
  size_t featB_bytes = (size_t)NB * NN * DORI * 2;                // 168 MB
  bool big = ws_size >= base_bytes + featB_bytes;
  u16* featB = big ? (u16*)ws : nullptr;

  // 1. fused prep + full-feature cast (one launch)
  prep_cast<<<PREP_TOTAL, 256, 0, stream>>>(features, att, w_q, w_q_cls, w_k, w_k_cls,
                                            alpha_w, bbox, alpha_w_cls, cls_w,
                                            gt_features, featB, attB, Wq, Wsmall);

  if (big) {
    // 2. off + smallf + cls, 128-tile, BK=64, swizzled LDS, XCD swizzle
    dim3 gm(5, 32, NB);
    gemm_main<<<gm, 256, 0, stream>>>(featB, attB, Wsmall, offb, smallf, out + O8);
  } else {
    dim3 g1(DAPP / 128, NN / 128, NB);
    gemm_af32<128, 128, 2, 2, true, true><<<g1, 256, 0, stream>>>(
        features, gt_features, (long)NN * DORI, attB, 0, offb, (long)NN * DAPP, DAPP, DORI);
    dim3 gsm(1, NN / 128, AN);
    gemm_af32<128, 32, 4, 1, false, false><<<gsm, 256, 0, stream>>>(
        features, nullptr, (long)NN * DORI, Wsmall, (long)32 * DORI,
        smallf, (long)NN * 32, 32, DORI);
    cls_copy<<<(AN * NN * NCLS + 255) / 256, 256, 0, stream>>>(smallf, out + O8);
  }

  // 3. key = gt_off @ Wq[9]^T (batch 9) -> keyf f32
  dim3 gk(QCOLS / 32, NN / 128, 1);
  gemm_glds<128, 32, 4, 1, false, false, false><<<gk, 256, 0, stream>>>(
      offb + (size_t)9 * NN * DAPP, 0, Wq + (size_t)9 * QCOLS * DAPP, 0,
      keyf, 0, QCOLS, DAPP);

  // 4. fused q-projection + beta (batches 0-8)
  dim3 g2(NN / 128, AN, 1);
  gemm2qb<<<g2, 256, 0, stream>>>(offb, Wq, keyf, ious, betaf, betac);

  // 5. softmaxes + outputs
  finalize<<<NN * 4 / 256, 256, 0, stream>>>(smallf, betaf, betac, delta_rois, out);
}

// Round 16
// 288.192 us; speedup vs baseline: 1.0355x; 1.0251x over previous
//
#include <hip/hip_runtime.h>

using u16 = unsigned short;
using s16x8 = __attribute__((ext_vector_type(8))) short;   // 8 bf16 (4 VGPRs)
using f32x4 = __attribute__((ext_vector_type(4))) float;

#define DEVI __device__ __forceinline__

constexpr int AN = 9, NB = 10, NN = 4096, DORI = 2048, DAPP = 512, NCLS = 21, QCOLS = 160;

// output offsets (f32 elements) in return order
constexpr size_t O0 = 0;                 // output            (4096,4)
constexpr size_t O1 = 16384;             // output_beta       (4096,4)
constexpr size_t O2 = 32768;             // alpha_softmax     (9,4096,4)
constexpr size_t O3 = 180224;            // beta_softmax      (9,4096,4)
constexpr size_t O4 = 327680;            // delta_pred_offset (9,4096,4)
constexpr size_t O5 = 475136;            // delta_pred_offset (9,4096,4)
constexpr size_t O6 = 622592;            // alpha             (9,4096,4)
constexpr size_t O7 = 770048;            // beta_out          (9,4096,4)
constexpr size_t O8 = 917504;            // cls_score         (9,4096,21)
constexpr size_t O9 = 1691648;           // alpha_softmax_cls (9,4096,1)
constexpr size_t O10 = 1728512;          // beta_softmax_cls
constexpr size_t O11 = 1765376;          // alpha_cls
constexpr size_t O12 = 1802240;          // beta_out_cls

// prep_cast block ranges
constexpr int CAST_B = 36864;            // AN*NN*DORI/8/256
constexpr int ATT_B  = 256;              // (2048/64)*(512/64)
constexpr int PQ_B   = 3200;             // NB*QCOLS*DAPP/256
constexpr int PS_B   = 72;               // AN*DORI/256
constexpr int GT_B   = 4096;             // NN*DORI/8/256
constexpr int PREP_TOTAL = CAST_B + ATT_B + PQ_B + PS_B + GT_B;   // 44488

DEVI u16 f2b(float f) {                   // f32 -> bf16 RNE (internal use only)
  unsigned u = __float_as_uint(f);
  unsigned r = (u + 0x7fffu + ((u >> 16) & 1u)) >> 16;
  return (u16)r;
}

DEVI uint4 pack8(float4 u, float4 v) {    // 8 f32 -> 8 bf16 packed
  uint4 r;
  r.x = (unsigned)f2b(u.x) | ((unsigned)f2b(u.y) << 16);
  r.y = (unsigned)f2b(u.z) | ((unsigned)f2b(u.w) << 16);
  r.z = (unsigned)f2b(v.x) | ((unsigned)f2b(v.y) << 16);
  r.w = (unsigned)f2b(v.z) | ((unsigned)f2b(v.w) << 16);
  return r;
}

DEVI void gload_lds16(const u16* g, u16* l) {   // 16B global -> LDS direct
  __builtin_amdgcn_global_load_lds(
      (const __attribute__((address_space(1))) void*)g,
      (__attribute__((address_space(3))) void*)l, 16, 0, 0);
}

// ================= prep_cast: cast | att-transpose | pack_q | pack_small | gt ======
__global__ __launch_bounds__(256) void prep_cast(const float* __restrict__ features,
                                                 const float* __restrict__ att,
                                                 const float* __restrict__ wq,
                                                 const float* __restrict__ wqc,
                                                 const float* __restrict__ wk,
                                                 const float* __restrict__ wkc,
                                                 const float* __restrict__ aw,
                                                 const float* __restrict__ bb,
                                                 const float* __restrict__ awc,
                                                 const float* __restrict__ cw,
                                                 const float* __restrict__ gt,
                                                 u16* __restrict__ featB,
                                                 u16* __restrict__ attB,
                                                 u16* __restrict__ Wq,
                                                 u16* __restrict__ Wsm) {
  __shared__ float tile[64][65];
  const int b = blockIdx.x, tid = threadIdx.x;
  if (b < CAST_B) {                                 // features f32 -> featB[0..8]
    if (!featB) return;
    long i = (long)b * 256 + tid;
    float4 v0 = ((const float4*)features)[i * 2];
    float4 v1 = ((const float4*)features)[i * 2 + 1];
    ((uint4*)featB)[i] = pack8(v0, v1);
  } else if (b < CAST_B + ATT_B) {                  // attB[c][d] = att[d][c], LDS tile
    int b2 = b - CAST_B;
    int d0 = (b2 >> 3) * 64, c0 = (b2 & 7) * 64;
#pragma unroll
    for (int r = 0; r < 16; ++r) {
      int dl = r * 4 + (tid >> 6), cl = tid & 63;
      tile[dl][cl] = att[(size_t)(d0 + dl) * DAPP + c0 + cl];
    }
    __syncthreads();
#pragma unroll
    for (int w = 0; w < 16; ++w) {
      int cl = w * 4 + (tid >> 6), dl = tid & 63;
      attB[(size_t)(c0 + cl) * DORI + d0 + dl] = f2b(tile[dl][cl]);
    }
  } else if (b < CAST_B + ATT_B + PQ_B) {           // Wq[b][160][512]
    int t = (b - CAST_B - ATT_B) * 256 + tid;
    int bq = t / (QCOLS * DAPP);
    int r = t % (QCOLS * DAPP);
    int col = r / DAPP, d = r % DAPP;
    float v;
    if (bq < 9) {
      if (col < 128) v = wq[(size_t)bq * DAPP * 128 + (size_t)d * 128 + col];
      else           v = wqc[(size_t)bq * DAPP * 32 + (size_t)d * 32 + (col - 128)];
    } else {
      if (col < 128) v = wk[(size_t)d * 128 + col];
      else           v = wkc[(size_t)d * 32 + (col - 128)];
    }
    Wq[t] = f2b(v);
  } else if (b < CAST_B + ATT_B + PQ_B + PS_B) {    // Wsmall[a][32][2048]
    int t = (b - CAST_B - ATT_B - PQ_B) * 256 + tid;
    if (t >= AN * DORI) return;
    int a = t / DORI, f = t % DORI;
    u16* Wa = Wsm + (size_t)a * 32 * DORI;
    for (int c = 0; c < 4; ++c)  Wa[c * DORI + f]       = f2b(aw[((size_t)a * DORI + f) * 4 + c]);
    for (int c = 0; c < 4; ++c)  Wa[(4 + c) * DORI + f] = f2b(bb[((size_t)a * DORI + f) * 4 + c]);
    for (int c = 0; c < 21; ++c) Wa[(8 + c) * DORI + f] = f2b(cw[((size_t)a * DORI + f) * 21 + c]);
    Wa[29 * DORI + f] = f2b(awc[(size_t)a * DORI + f]);
    Wa[30 * DORI + f] = 0;
    Wa[31 * DORI + f] = 0;
  } else {                                          // gt_features -> featB[9]
    if (!featB) return;
    long i = (long)(b - CAST_B - ATT_B - PQ_B - PS_B) * 256 + tid;
    float4 v0 = ((const float4*)gt)[i * 2];
    float4 v1 = ((const float4*)gt)[i * 2 + 1];
    ((uint4*)(featB + (size_t)AN * NN * DORI))[i] = pack8(v0, v1);
  }
}

// ================= gemm_main: 128x128(+small), BK=64, PANEL-LOCAL XCD swizzle ======
// grid (5, 32, 10), 256 threads; bx<4: off 128x128 (wave 64x64), bx==4: smallf
// 128x32 (wave 32x32). LDS [row][64]: physical chunk p holds logical kc = p^(row&7).
// Swizzle change vs r13/15: the 5 bx blocks sharing one A-panel now land on the
// SAME XCD back-to-back (r13 spread them over 5 XCDs) -> A-panel read hits L2
// instead of HBM for 4 of 5 readers. Pure bijective index permutation.
__global__ __launch_bounds__(256) void gemm_main(const u16* __restrict__ featB,
                                                 const u16* __restrict__ attB,
                                                 const u16* __restrict__ Wsm,
                                                 u16* __restrict__ offb,
                                                 float* __restrict__ smallf,
                                                 float* __restrict__ cls_out) {
  __shared__ __align__(16) u16 As[128 * 64];   // 16 KB
  __shared__ __align__(16) u16 Bs[128 * 64];   // 16 KB

  int bx, by, bz;
  {                                   // panel-local: 1600 blocks = 8 XCD x 200
    int h = blockIdx.x + 5 * (blockIdx.y + 32 * blockIdx.z);
    int x = h & 7, r = h >> 3;        // x = XCD, r in [0,200)
    bx = r % 5;
    int p = (r / 5) * 8 + x;          // panel in [0,320), p&7 == XCD
    by = p & 31; bz = p >> 5;
  }
  const int tid = threadIdx.x, lane = tid & 63, w = tid >> 6;
  const bool small = (bx == 4);
  if (small && bz == 9) return;       // no small path for gt batch
  const int tileM = by * 128;
  const u16* Ab = featB + ((size_t)bz * NN + tileM) * DORI;
  const u16* Bb = small ? (Wsm + (size_t)bz * 32 * DORI)
                        : (attB + (size_t)bx * 128 * DORI);

  f32x4 accM[4][4], accS[2][2];
#pragma unroll
  for (int i = 0; i < 4; ++i)
#pragma unroll
    for (int j = 0; j < 4; ++j) accM[i][j] = (f32x4){0.f, 0.f, 0.f, 0.f};
#pragma unroll
  for (int i = 0; i < 2; ++i)
#pragma unroll
    for (int j = 0; j < 2; ++j) accS[i][j] = (f32x4){0.f, 0.f, 0.f, 0.f};

  const int wm = w & 1, wn = w >> 1;

  // stage swizzle: chunk c -> row = c>>3, phys = c&7, logical kc = phys ^ (row&7)
  int arow[4], acol[4];
#pragma unroll
  for (int i = 0; i < 4; ++i) {
    int c = tid + i * 256;
    arow[i] = c >> 3;
    acol[i] = (((c & 7) ^ ((c >> 3) & 7))) * 8;
  }
  // read swizzle: row&7 = lane&7 (row = 16*b + (lane&15));
  // logical chunk lc = mk*4 + (lane>>4); phys = lc ^ (lane&7)
  const int lanerow = (lane & 15) * 64;
  const int ph0 = (((lane >> 4)) ^ (lane & 7)) * 8;        // mk = 0
  const int ph1 = (((lane >> 4) + 4) ^ (lane & 7)) * 8;    // mk = 1

  for (int k0 = 0; k0 < DORI; k0 += 64) {
#pragma unroll
    for (int i = 0; i < 4; ++i)
      gload_lds16(Ab + (size_t)arow[i] * DORI + k0 + acol[i], As + (tid + i * 256) * 8);
    if (small) {
      // B: 32 rows x 8 chunks = 256 chunks, one per thread
      gload_lds16(Bb + (size_t)(tid >> 3) * DORI + k0 + (((tid & 7) ^ ((tid >> 3) & 7)) * 8),
                  Bs + tid * 8);
    } else {
#pragma unroll
      for (int i = 0; i < 4; ++i)
        gload_lds16(Bb + (size_t)arow[i] * DORI + k0 + acol[i], Bs + (tid + i * 256) * 8);
    }
    __syncthreads();
    if (small) {
#pragma unroll
      for (int mk = 0; mk < 2; ++mk) {
        const int ph = mk ? ph1 : ph0;
        s16x8 af[2], bf[2];
#pragma unroll
        for (int i = 0; i < 2; ++i)
          af[i] = *(const s16x8*)(As + (w * 32 + i * 16) * 64 + lanerow + ph);
#pragma unroll
        for (int j = 0; j < 2; ++j)
          bf[j] = *(const s16x8*)(Bs + (j * 16) * 64 + lanerow + ph);
#pragma unroll
        for (int i = 0; i < 2; ++i)
#pragma unroll
          for (int j = 0; j < 2; ++j)
            accS[i][j] = __builtin_amdgcn_mfma_f32_16x16x32_bf16(af[i], bf[j], accS[i][j], 0, 0, 0);
      }
    } else {
#pragma unroll
      for (int mk = 0; mk < 2; ++mk) {
        const int ph = mk ? ph1 : ph0;
        s16x8 af[4], bf[4];
#pragma unroll
        for (int i = 0; i < 4; ++i)
          af[i] = *(const s16x8*)(As + (wm * 64 + i * 16) * 64 + lanerow + ph);
#pragma unroll
        for (int j = 0; j < 4; ++j)
          bf[j] = *(const s16x8*)(Bs + (wn * 64 + j * 16) * 64 + lanerow + ph);
#pragma unroll
        for (int i = 0; i < 4; ++i)
#pragma unroll
          for (int j = 0; j < 4; ++j)
            accM[i][j] = __builtin_amdgcn_mfma_f32_16x16x32_bf16(af[i], bf[j], accM[i][j], 0, 0, 0);
      }
    }
    __syncthreads();
  }

  if (small) {
#pragma unroll
    for (int i = 0; i < 2; ++i)
#pragma unroll
      for (int j = 0; j < 2; ++j)
#pragma unroll
        for (int q = 0; q < 4; ++q) {
          const int row = tileM + w * 32 + i * 16 + (lane >> 4) * 4 + q;
          const int col = j * 16 + (lane & 15);
          const size_t an = (size_t)bz * NN + row;
          float v = accS[i][j][q];
          smallf[an * 32 + col] = v;
          if (col >= 8 && col <= 28) cls_out[an * 21 + (col - 8)] = v;
        }
  } else {
    const int r0 = tileM + wm * 64 + (lane >> 4) * 4;
    const int c0 = bx * 128 + wn * 64 + (lane & 15);
#pragma unroll
    for (int i = 0; i < 4; ++i)
#pragma unroll
      for (int j = 0; j < 4; ++j)
#pragma unroll
        for (int q = 0; q < 4; ++q)
          offb[((size_t)bz * NN + r0 + i * 16 + q) * DAPP + c0 + j * 16] =
              f2b(fmaxf(accM[i][j][q], 0.f));
  }
}

// ================= bf16 GEMM, glds staging, 2-phase dbuf (key path) ================
template<int BM, int BN, int WM, int WN, bool RELU, bool OUTBF, bool SWZ>
__global__ __launch_bounds__(WM * WN * 64)
void gemm_glds(const u16* __restrict__ A, long sA, const u16* __restrict__ B, long sB,
               void* __restrict__ Cv, long sC, int N, int K) {
  constexpr int THREADS = WM * WN * 64;
  constexpr int WTM = BM / WM, WTN = BN / WN;
  constexpr int FM = WTM / 16, FN = WTN / 16;
  constexpr int ACHN = BM * 4, BCHN = BN * 4;
  constexpr int ACH = (ACHN + THREADS - 1) / THREADS;
  constexpr int BCH = (BCHN + THREADS - 1) / THREADS;
  constexpr bool AFULL = (ACHN % THREADS) == 0, BFULL = (BCHN % THREADS) == 0;

  __shared__ __align__(16) u16 As[2][BM * 32];
  __shared__ __align__(16) u16 Bs[2][BN * 32];

  int bx = blockIdx.x, by = blockIdx.y, bz = blockIdx.z;
  if constexpr (SWZ) {
    int gx = gridDim.x, gy = gridDim.y;
    int h = bx + gx * (by + gy * bz);
    int nwg = gx * gy * (int)gridDim.z;
    int cpx = nwg >> 3;
    int l = (h & 7) * cpx + (h >> 3);
    bx = l % gx; l /= gx; by = l % gy; bz = l / gy;
  }

  const int tid = threadIdx.x, lane = tid & 63, wave = tid >> 6;
  const int wm = wave % WM, wn = wave / WM;
  const int tileN = bx * BN, tileM = by * BM;
  const u16* Ab = A + (size_t)bz * sA + (size_t)tileM * K;
  const u16* Bb = B + (size_t)bz * sB + (size_t)tileN * K;

  f32x4 acc[FM][FN];
#pragma unroll
  for (int i = 0; i < FM; ++i)
#pragma unroll
    for (int j = 0; j < FN; ++j) acc[i][j] = (f32x4){0.f, 0.f, 0.f, 0.f};

  auto stage = [&](int buf, int k0) {
#pragma unroll
    for (int i = 0; i < ACH; ++i) {
      int c = tid + i * THREADS;
      if (AFULL || c < ACHN)
        gload_lds16(Ab + (size_t)(c >> 2) * K + k0 + (c & 3) * 8, As[buf] + c * 8);
    }
#pragma unroll
    for (int i = 0; i < BCH; ++i) {
      int c = tid + i * THREADS;
      if (BFULL || c < BCHN)
        gload_lds16(Bb + (size_t)(c >> 2) * K + k0 + (c & 3) * 8, Bs[buf] + c * 8);
    }
  };

  stage(0, 0);
  __syncthreads();
  int cur = 0;
  for (int k0 = 0; k0 < K; k0 += 32) {
    if (k0 + 32 < K) stage(cur ^ 1, k0 + 32);
    const u16* Arow = As[cur] + (wm * WTM + (lane & 15)) * 32 + (lane >> 4) * 8;
    const u16* Brow = Bs[cur] + (wn * WTN + (lane & 15)) * 32 + (lane >> 4) * 8;
    s16x8 af[FM], bfr[FN];
#pragma unroll
    for (int i = 0; i < FM; ++i) af[i] = *(const s16x8*)(Arow + i * 16 * 32);
#pragma unroll
    for (int j = 0; j < FN; ++j) bfr[j] = *(const s16x8*)(Brow + j * 16 * 32);
#pragma unroll
    for (int i = 0; i < FM; ++i)
#pragma unroll
      for (int j = 0; j < FN; ++j)
        acc[i][j] = __builtin_amdgcn_mfma_f32_16x16x32_bf16(af[i], bfr[j], acc[i][j], 0, 0, 0);
    __syncthreads();
    cur ^= 1;
  }

  const int r0 = tileM + wm * WTM + (lane >> 4) * 4;
  const int c0 = tileN + wn * WTN + (lane & 15);
#pragma unroll
  for (int i = 0; i < FM; ++i)
#pragma unroll
    for (int j = 0; j < FN; ++j)
#pragma unroll
      for (int q = 0; q < 4; ++q) {
        float v = acc[i][j][q];
        if (RELU) v = fmaxf(v, 0.f);
        size_t idx = (size_t)bz * sC + (size_t)(r0 + i * 16 + q) * N + (c0 + j * 16);
        if (OUTBF) ((u16*)Cv)[idx] = f2b(v);
        else       ((float*)Cv)[idx] = v;
      }
}

// ================= fallback gemm (A = f32, reg-staged pack) ========================
template<int BM, int BN, int WM, int WN, bool RELU, bool OUTBF>
__global__ __launch_bounds__(WM * WN * 64)
void gemm_af32(const float* __restrict__ Av, const float* __restrict__ A2v, long sA,
               const u16* __restrict__ B, long sB,
               void* __restrict__ Cv, long sC, int N, int K) {
  constexpr int THREADS = WM * WN * 64;
  constexpr int WTM = BM / WM, WTN = BN / WN;
  constexpr int FM = WTM / 16, FN = WTN / 16;
  constexpr int ACH = (BM * 4) / THREADS;
  constexpr int BCHN = BN * 4;
  constexpr int BCH = (BCHN + THREADS - 1) / THREADS;
  constexpr bool BFULL = (BCHN % THREADS) == 0;

  __shared__ __align__(16) u16 As[BM * 32];
  __shared__ __align__(16) u16 Bs[BN * 32];

  const int tid = threadIdx.x, lane = tid & 63, wave = tid >> 6;
  const int wm = wave % WM, wn = wave / WM;
  const int tileN = blockIdx.x * BN, tileM = blockIdx.y * BM;
  const int batch = blockIdx.z;
  const float* base = (batch < 9) ? (Av + (size_t)batch * sA) : A2v;
  const float* Ab32 = base + (size_t)tileM * K;
  const u16* Bb = B + (size_t)batch * sB + (size_t)tileN * K;

  f32x4 acc[FM][FN];
#pragma unroll
  for (int i = 0; i < FM; ++i)
#pragma unroll
    for (int j = 0; j < FN; ++j) acc[i][j] = (f32x4){0.f, 0.f, 0.f, 0.f};

  uint4 ra[ACH], rb[BCH];
  auto load_t = [&](int k0) {
#pragma unroll
    for (int i = 0; i < ACH; ++i) {
      int c = tid + i * THREADS;
      const float* s = Ab32 + (size_t)(c >> 2) * K + k0 + (c & 3) * 8;
      ra[i] = pack8(*(const float4*)s, *(const float4*)(s + 4));
    }
#pragma unroll
    for (int i = 0; i < BCH; ++i) {
      int c = tid + i * THREADS;
      if (BFULL || c < BCHN)
        rb[i] = *(const uint4*)(Bb + (size_t)(c >> 2) * K + k0 + (c & 3) * 8);
    }
  };

  load_t(0);
  const u16* Arow = As + (wm * WTM + (lane & 15)) * 32 + (lane >> 4) * 8;
  const u16* Brow = Bs + (wn * WTN + (lane & 15)) * 32 + (lane >> 4) * 8;

  for (int k0 = 0; k0 < K; k0 += 32) {
    __syncthreads();
#pragma unroll
    for (int i = 0; i < ACH; ++i)
      *(uint4*)(As + (size_t)(tid + i * THREADS) * 8) = ra[i];
#pragma unroll
    for (int i = 0; i < BCH; ++i) {
      int c = tid + i * THREADS;
      if (BFULL || c < BCHN) *(uint4*)(Bs + (size_t)c * 8) = rb[i];
    }
    __syncthreads();
    if (k0 + 32 < K) load_t(k0 + 32);
    s16x8 af[FM], bfr[FN];
#pragma unroll
    for (int i = 0; i < FM; ++i) af[i] = *(const s16x8*)(Arow + i * 16 * 32);
#pragma unroll
    for (int j = 0; j < FN; ++j) bfr[j] = *(const s16x8*)(Brow + j * 16 * 32);
#pragma unroll
    for (int i = 0; i < FM; ++i)
#pragma unroll
      for (int j = 0; j < FN; ++j)
        acc[i][j] = __builtin_amdgcn_mfma_f32_16x16x32_bf16(af[i], bfr[j], acc[i][j], 0, 0, 0);
  }

  const int r0 = tileM + wm * WTM + (lane >> 4) * 4;
  const int c0 = tileN + wn * WTN + (lane & 15);
#pragma unroll
  for (int i = 0; i < FM; ++i)
#pragma unroll
    for (int j = 0; j < FN; ++j)
#pragma unroll
      for (int q = 0; q < 4; ++q) {
        float v = acc[i][j][q];
        if (RELU) v = fmaxf(v, 0.f);
        size_t idx = (size_t)batch * sC + (size_t)(r0 + i * 16 + q) * N + (c0 + j * 16);
        if (OUTBF) ((u16*)Cv)[idx] = f2b(v);
        else       ((float*)Cv)[idx] = v;
      }
}

// ================= cls copy (fallback path only) ===================================
__global__ __launch_bounds__(256) void cls_copy(const float* __restrict__ smallf,
                                                float* __restrict__ o) {
  int i = blockIdx.x * blockDim.x + threadIdx.x;
  if (i >= AN * NN * NCLS) return;
  int an = i / NCLS, c = i % NCLS;
  o[i] = smallf[(size_t)an * 32 + 8 + c];
}

// ================= fused q-projection + beta epilogue, 2-phase dbuf ================
__global__ __launch_bounds__(256) void gemm2qb(const u16* __restrict__ offb,
                                               const u16* __restrict__ Wq,
                                               const float* __restrict__ keyf,
                                               const float* __restrict__ ious,
                                               float* __restrict__ betaf,
                                               float* __restrict__ betac) {
  constexpr int BM = 128, BN = 160;
  __shared__ __align__(16) u16 As[2][BM * 32];
  __shared__ __align__(16) u16 Bs[2][BN * 32];
  const int tid = threadIdx.x, lane = tid & 63, wave = tid >> 6;  // 4 waves on M
  const int tileM = blockIdx.x * BM;
  const int a = blockIdx.y;
  const u16* Ab = offb + ((size_t)a * NN + tileM) * DAPP;
  const u16* Bb = Wq + (size_t)a * QCOLS * DAPP;

  f32x4 acc[2][10];
#pragma unroll
  for (int i = 0; i < 2; ++i)
#pragma unroll
    for (int j = 0; j < 10; ++j) acc[i][j] = (f32x4){0.f, 0.f, 0.f, 0.f};

  auto stage = [&](int buf, int k0) {
#pragma unroll
    for (int i = 0; i < 2; ++i) {          // ACHN = 512
      int c = tid + i * 256;
      gload_lds16(Ab + (size_t)(c >> 2) * DAPP + k0 + (c & 3) * 8, As[buf] + c * 8);
    }
#pragma unroll
    for (int i = 0; i < 3; ++i) {          // BCHN = 640
      int c = tid + i * 256;
      if (c < 640)
        gload_lds16(Bb + (size_t)(c >> 2) * DAPP + k0 + (c & 3) * 8, Bs[buf] + c * 8);
    }
  };

  stage(0, 0);
  __syncthreads();
  int cur = 0;
  for (int k0 = 0; k0 < DAPP; k0 += 32) {
    if (k0 + 32 < DAPP) stage(cur ^ 1, k0 + 32);
    const u16* Arow = As[cur] + (wave * 32 + (lane & 15)) * 32 + (lane >> 4) * 8;
    const u16* Brow = Bs[cur] + (lane & 15) * 32 + (lane >> 4) * 8;
    s16x8 af[2], bfr[10];
#pragma unroll
    for (int i = 0; i < 2; ++i) af[i] = *(const s16x8*)(Arow + i * 16 * 32);
#pragma unroll
    for (int j = 0; j < 10; ++j) bfr[j] = *(const s16x8*)(Brow + j * 16 * 32);
#pragma unroll
    for (int i = 0; i < 2; ++i)
#pragma unroll
      for (int j = 0; j < 10; ++j)
        acc[i][j] = __builtin_amdgcn_mfma_f32_16x16x32_bf16(af[i], bfr[j], acc[i][j], 0, 0, 0);
    __syncthreads();
    cur ^= 1;
  }

  const float scale = 0.17677669529663687f;  // 1/sqrt(32)
  const int cg = lane & 15;
#pragma unroll
  for (int i = 0; i < 2; ++i)
#pragma unroll
    for (int q = 0; q < 4; ++q) {
      const int row = tileM + wave * 32 + i * 16 + (lane >> 4) * 4 + q;
      const float* kr = keyf + (size_t)row * QCOLS;
      float m = 0.f;
#pragma unroll
      for (int j = 0; j < 8; ++j) m += acc[i][j][q] * kr[cg + j * 16];
      float cl = acc[i][8][q] * kr[128 + cg] + acc[i][9][q] * kr[144 + cg];
      m += __shfl_xor(m, 4); m += __shfl_xor(m, 8);
      cl += __shfl_xor(cl, 1); cl += __shfl_xor(cl, 2);
      cl += __shfl_xor(cl, 4); cl += __shfl_xor(cl, 8);
      const float iou = ious[(size_t)a * NN + row];
      if (cg < 4)  betaf[((size_t)a * NN + row) * 4 + (lane & 3)] = m * scale - iou;
      if (cg == 0) betac[(size_t)a * NN + row] = cl * scale - iou;
    }
}

// ================= softmaxes + outputs, thread per (n,c) ===========================
__global__ __launch_bounds__(256) void finalize(const float* __restrict__ smallf,
                                                const float* __restrict__ beta_ws,
                                                const float* __restrict__ betac_ws,
                                                const float* __restrict__ delta_rois,
                                                float* __restrict__ out) {
  int t = blockIdx.x * 256 + threadIdx.x;      // grid = NN*4/256 = 64
  if (t >= NN * 4) return;
  const int n = t >> 2, c = t & 3;

  {
    float al[9], be[9], dp[9];
    float mA = -1e30f, mB = -1e30f;
    for (int a = 0; a < 9; ++a) {
      size_t an = (size_t)a * NN + n;
      al[a] = smallf[an * 32 + c];
      float off_ = smallf[an * 32 + 4 + c];
      dp[a] = delta_rois[an * 5 + 1 + c] + off_;
      be[a] = beta_ws[an * 4 + c];
      mA = fmaxf(mA, al[a]); mB = fmaxf(mB, be[a]);
    }
    float eA[9], eB[9], sA = 0.f, sB = 0.f;
    for (int a = 0; a < 9; ++a) {
      eA[a] = expf(al[a] - mA); sA += eA[a];
      eB[a] = expf(be[a] - mB); sB += eB[a];
    }
    float rA = 1.f / sA, rB = 1.f / sB;
    float ov = 0.f, obv = 0.f;
    for (int a = 0; a < 9; ++a) {
      size_t an = (size_t)a * NN + n;
      float as_ = eA[a] * rA, bs_ = eB[a] * rB;
      out[O2 + an * 4 + c] = as_;
      out[O3 + an * 4 + c] = bs_;
      out[O4 + an * 4 + c] = dp[a];
      out[O5 + an * 4 + c] = dp[a];
      out[O6 + an * 4 + c] = al[a];
      out[O7 + an * 4 + c] = be[a];
      ov += dp[a] * as_; obv += dp[a] * bs_;
    }
    out[O0 + (size_t)n * 4 + c] = ov;
    out[O1 + (size_t)n * 4 + c] = obv;
  }

  if (c == 0) {
    float ac[9], bc[9];
    float mA = -1e30f, mB = -1e30f;
    for (int a = 0; a < 9; ++a) {
      size_t an = (size_t)a * NN + n;
      ac[a] = smallf[an * 32 + 29];
      bc[a] = betac_ws[an];
      mA = fmaxf(mA, ac[a]); mB = fmaxf(mB, bc[a]);
    }
    float eA[9], eB[9], sA = 0.f, sB = 0.f;
    for (int a = 0; a < 9; ++a) {
      eA[a] = expf(ac[a] - mA); sA += eA[a];
      eB[a] = expf(bc[a] - mB); sB += eB[a];
    }
    float rA = 1.f / sA, rB = 1.f / sB;
    for (int a = 0; a < 9; ++a) {
      size_t an = (size_t)a * NN + n;
      out[O9 + an]  = eA[a] * rA;
      out[O10 + an] = eB[a] * rB;
      out[O11 + an] = ac[a];
      out[O12 + an] = bc[a];
    }
  }
}

extern "C" void kernel_launch(void* const* d_in, const int* in_sizes, int n_in,
                              void* d_out, int out_size, void* d_ws, size_t ws_size,
                              hipStream_t stream) {
  const float* delta_rois = (const float*)d_in[1];
  const float* features   = (const float*)d_in[2];
  const float* gt_features= (const float*)d_in[3];
  const float* ious       = (const float*)d_in[4];
  const float* att        = (const float*)d_in[5];
  const float* w_k        = (const float*)d_in[6];
  const float* w_q        = (const float*)d_in[7];
  const float* alpha_w    = (const float*)d_in[8];
  const float* bbox       = (const float*)d_in[9];
  const float* w_k_cls    = (const float*)d_in[10];
  const float* w_q_cls    = (const float*)d_in[11];
  const float* alpha_w_cls= (const float*)d_in[12];
  const float* cls_w      = (const float*)d_in[13];
  float* out = (float*)d_out;

  char* ws = (char*)d_ws;
  u16* attB    = (u16*)ws;   ws += (size_t)DAPP * DORI * 2;       // 2.1 MB
  u16* Wq      = (u16*)ws;   ws += (size_t)NB * QCOLS * DAPP * 2; // 1.6 MB
  u16* Wsmall  = (u16*)ws;   ws += (size_t)AN * 32 * DORI * 2;    // 1.2 MB
  u16* offb    = (u16*)ws;   ws += (size_t)NB * NN * DAPP * 2;    // 42 MB (batch9 = gt_off)
  float* smallf= (float*)ws; ws += (size_t)AN * NN * 32 * 4;      // 4.7 MB
  float* keyf  = (float*)ws; ws += (size_t)NN * QCOLS * 4;        // 2.6 MB
  float* betaf = (float*)ws; ws += (size_t)AN * NN * 4 * 4;       // 2.4 MB
  float* betac = (float*)ws; ws += (size_t)AN * NN * 4;           // 0.15 MB
  size_t base_bytes = (size_t)(ws - (char*)d_ws);
  size_t featB_bytes = (size_t)NB * NN * DORI * 2;                // 168 MB
  bool big = ws_size >= base_bytes + featB_bytes;
  u16* featB = big ? (u16*)ws : nullptr;

  // 1. fused prep + full-feature cast (one launch)
  prep_cast<<<PREP_TOTAL, 256, 0, stream>>>(features, att, w_q, w_q_cls, w_k, w_k_cls,
                                            alpha_w, bbox, alpha_w_cls, cls_w,
                                            gt_features, featB, attB, Wq, Wsmall);

  if (big) {
    // 2. off + smallf + cls, 128-tile, BK=64, swizzled LDS, panel-local XCD swizzle
    dim3 gm(5, 32, NB);
    gemm_main<<<gm, 256, 0, stream>>>(featB, attB, Wsmall, offb, smallf, out + O8);
  } else {
    dim3 g1(DAPP / 128, NN / 128, NB);
    gemm_af32<128, 128, 2, 2, true, true><<<g1, 256, 0, stream>>>(
        features, gt_features, (long)NN * DORI, attB, 0, offb, (long)NN * DAPP, DAPP, DORI);
    dim3 gsm(1, NN / 128, AN);
    gemm_af32<128, 32, 4, 1, false, false><<<gsm, 256, 0, stream>>>(
        features, nullptr, (long)NN * DORI, Wsmall, (long)32 * DORI,
        smallf, (long)NN * 32, 32, DORI);
    cls_copy<<<(AN * NN * NCLS + 255) / 256, 256, 0, stream>>>(smallf, out + O8);
  }

  // 3. key = gt_off @ Wq[9]^T (batch 9) -> keyf f32
  dim3 gk(QCOLS / 32, NN / 128, 1);
  gemm_glds<128, 32, 4, 1, false, false, false><<<gk, 256, 0, stream>>>(
      offb + (size_t)9 * NN * DAPP, 0, Wq + (size_t)9 * QCOLS * DAPP, 0,
      keyf, 0, QCOLS, DAPP);

  // 4. fused q-projection + beta (batches 0-8)
  dim3 g2(NN / 128, AN, 1);
  gemm2qb<<<g2, 256, 0, stream>>>(offb, Wq, keyf, ious, betaf, betac);

  // 5. softmaxes + outputs
  finalize<<<NN * 4 / 256, 256, 0, stream>>>(smallf, betaf, betac, delta_rois, out);
}

// Round 17
// 274.054 us; speedup vs baseline: 1.0889x; 1.0516x over previous
//
#include <hip/hip_runtime.h>

using u16 = unsigned short;
using s16x8 = __attribute__((ext_vector_type(8))) short;   // 8 bf16 (4 VGPRs)
using f32x4 = __attribute__((ext_vector_type(4))) float;

#define DEVI __device__ __forceinline__

constexpr int AN = 9, NB = 10, NN = 4096, DORI = 2048, DAPP = 512, NCLS = 21, QCOLS = 160;

// output offsets (f32 elements) in return order
constexpr size_t O0 = 0;                 // output            (4096,4)
constexpr size_t O1 = 16384;             // output_beta       (4096,4)
constexpr size_t O2 = 32768;             // alpha_softmax     (9,4096,4)
constexpr size_t O3 = 180224;            // beta_softmax      (9,4096,4)
constexpr size_t O4 = 327680;            // delta_pred_offset (9,4096,4)
constexpr size_t O5 = 475136;            // delta_pred_offset (9,4096,4)
constexpr size_t O6 = 622592;            // alpha             (9,4096,4)
constexpr size_t O7 = 770048;            // beta_out          (9,4096,4)
constexpr size_t O8 = 917504;            // cls_score         (9,4096,21)
constexpr size_t O9 = 1691648;           // alpha_softmax_cls (9,4096,1)
constexpr size_t O10 = 1728512;          // beta_softmax_cls
constexpr size_t O11 = 1765376;          // alpha_cls
constexpr size_t O12 = 1802240;          // beta_out_cls

// prep_cast block ranges
constexpr int CAST_B = 36864;            // AN*NN*DORI/8/256
constexpr int ATT_B  = 256;              // (2048/64)*(512/64)
constexpr int PQ_B   = 3200;             // NB*QCOLS*DAPP/256
constexpr int PS_B   = 72;               // AN*DORI/256
constexpr int GT_B   = 4096;             // NN*DORI/8/256
constexpr int PREP_TOTAL = CAST_B + ATT_B + PQ_B + PS_B + GT_B;   // 44488

DEVI u16 f2b(float f) {                   // f32 -> bf16 RNE (internal use only)
  unsigned u = __float_as_uint(f);
  unsigned r = (u + 0x7fffu + ((u >> 16) & 1u)) >> 16;
  return (u16)r;
}

DEVI uint4 pack8(float4 u, float4 v) {    // 8 f32 -> 8 bf16 packed
  uint4 r;
  r.x = (unsigned)f2b(u.x) | ((unsigned)f2b(u.y) << 16);
  r.y = (unsigned)f2b(u.z) | ((unsigned)f2b(u.w) << 16);
  r.z = (unsigned)f2b(v.x) | ((unsigned)f2b(v.y) << 16);
  r.w = (unsigned)f2b(v.z) | ((unsigned)f2b(v.w) << 16);
  return r;
}

DEVI void gload_lds16(const u16* g, u16* l) {   // 16B global -> LDS direct
  __builtin_amdgcn_global_load_lds(
      (const __attribute__((address_space(1))) void*)g,
      (__attribute__((address_space(3))) void*)l, 16, 0, 0);
}

// ================= prep_cast: cast | att-transpose | pack_q | pack_small | gt ======
__global__ __launch_bounds__(256) void prep_cast(const float* __restrict__ features,
                                                 const float* __restrict__ att,
                                                 const float* __restrict__ wq,
                                                 const float* __restrict__ wqc,
                                                 const float* __restrict__ wk,
                                                 const float* __restrict__ wkc,
                                                 const float* __restrict__ aw,
                                                 const float* __restrict__ bb,
                                                 const float* __restrict__ awc,
                                                 const float* __restrict__ cw,
                                                 const float* __restrict__ gt,
                                                 u16* __restrict__ featB,
                                                 u16* __restrict__ attB,
                                                 u16* __restrict__ Wq,
                                                 u16* __restrict__ Wsm) {
  __shared__ float tile[64][65];
  const int b = blockIdx.x, tid = threadIdx.x;
  if (b < CAST_B) {                                 // features f32 -> featB[0..8]
    if (!featB) return;
    long i = (long)b * 256 + tid;
    float4 v0 = ((const float4*)features)[i * 2];
    float4 v1 = ((const float4*)features)[i * 2 + 1];
    ((uint4*)featB)[i] = pack8(v0, v1);
  } else if (b < CAST_B + ATT_B) {                  // attB[c][d] = att[d][c], LDS tile
    int b2 = b - CAST_B;
    int d0 = (b2 >> 3) * 64, c0 = (b2 & 7) * 64;
#pragma unroll
    for (int r = 0; r < 16; ++r) {
      int dl = r * 4 + (tid >> 6), cl = tid & 63;
      tile[dl][cl] = att[(size_t)(d0 + dl) * DAPP + c0 + cl];
    }
    __syncthreads();
#pragma unroll
    for (int w = 0; w < 16; ++w) {
      int cl = w * 4 + (tid >> 6), dl = tid & 63;
      attB[(size_t)(c0 + cl) * DORI + d0 + dl] = f2b(tile[dl][cl]);
    }
  } else if (b < CAST_B + ATT_B + PQ_B) {           // Wq[b][160][512]
    int t = (b - CAST_B - ATT_B) * 256 + tid;
    int bq = t / (QCOLS * DAPP);
    int r = t % (QCOLS * DAPP);
    int col = r / DAPP, d = r % DAPP;
    float v;
    if (bq < 9) {
      if (col < 128) v = wq[(size_t)bq * DAPP * 128 + (size_t)d * 128 + col];
      else           v = wqc[(size_t)bq * DAPP * 32 + (size_t)d * 32 + (col - 128)];
    } else {
      if (col < 128) v = wk[(size_t)d * 128 + col];
      else           v = wkc[(size_t)d * 32 + (col - 128)];
    }
    Wq[t] = f2b(v);
  } else if (b < CAST_B + ATT_B + PQ_B + PS_B) {    // Wsmall[a][32][2048]
    int t = (b - CAST_B - ATT_B - PQ_B) * 256 + tid;
    if (t >= AN * DORI) return;
    int a = t / DORI, f = t % DORI;
    u16* Wa = Wsm + (size_t)a * 32 * DORI;
    for (int c = 0; c < 4; ++c)  Wa[c * DORI + f]       = f2b(aw[((size_t)a * DORI + f) * 4 + c]);
    for (int c = 0; c < 4; ++c)  Wa[(4 + c) * DORI + f] = f2b(bb[((size_t)a * DORI + f) * 4 + c]);
    for (int c = 0; c < 21; ++c) Wa[(8 + c) * DORI + f] = f2b(cw[((size_t)a * DORI + f) * 21 + c]);
    Wa[29 * DORI + f] = f2b(awc[(size_t)a * DORI + f]);
    Wa[30 * DORI + f] = 0;
    Wa[31 * DORI + f] = 0;
  } else {                                          // gt_features -> featB[9]
    if (!featB) return;
    long i = (long)(b - CAST_B - ATT_B - PQ_B - PS_B) * 256 + tid;
    float4 v0 = ((const float4*)gt)[i * 2];
    float4 v1 = ((const float4*)gt)[i * 2 + 1];
    ((uint4*)(featB + (size_t)AN * NN * DORI))[i] = pack8(v0, v1);
  }
}

// ================= gemm_main: 128x128, BK=64, 8 waves x 32x64 tiles ================
// grid (5, 32, 10), 512 threads / 8 waves; bx<4: off (wave 32x64, acc=32 AGPR),
// bx==4: smallf (wave 16x32, acc=8). Register-occupancy lever: r8-r16 all sat at
// ~180 regs/wave (116 VGPR + 64 AGPR acc) -> 2 waves/SIMD -> 8 waves/CU. Halving
// per-wave acc + launch_bounds(512,4) targets 4 waves/SIMD = 16 waves/CU.
// LDS + swizzles identical to r13/r15 (verified).
__global__ __launch_bounds__(512, 4) void gemm_main(const u16* __restrict__ featB,
                                                    const u16* __restrict__ attB,
                                                    const u16* __restrict__ Wsm,
                                                    u16* __restrict__ offb,
                                                    float* __restrict__ smallf,
                                                    float* __restrict__ cls_out) {
  __shared__ __align__(16) u16 As[128 * 64];   // 16 KB
  __shared__ __align__(16) u16 Bs[128 * 64];   // 16 KB

  int bx, by, bz;
  {                                   // panel-local: 1600 blocks = 8 XCD x 200
    int h = blockIdx.x + 5 * (blockIdx.y + 32 * blockIdx.z);
    int x = h & 7, r = h >> 3;        // x = XCD, r in [0,200)
    bx = r % 5;
    int p = (r / 5) * 8 + x;          // panel in [0,320), p&7 == XCD
    by = p & 31; bz = p >> 5;
  }
  const int tid = threadIdx.x, lane = tid & 63, w = tid >> 6;
  const bool small = (bx == 4);
  if (small && bz == 9) return;       // no small path for gt batch
  const int tileM = by * 128;
  const u16* Ab = featB + ((size_t)bz * NN + tileM) * DORI;
  const u16* Bb = small ? (Wsm + (size_t)bz * 32 * DORI)
                        : (attB + (size_t)bx * 128 * DORI);

  f32x4 accM[2][4], accS[2];
#pragma unroll
  for (int i = 0; i < 2; ++i)
#pragma unroll
    for (int j = 0; j < 4; ++j) accM[i][j] = (f32x4){0.f, 0.f, 0.f, 0.f};
#pragma unroll
  for (int j = 0; j < 2; ++j) accS[j] = (f32x4){0.f, 0.f, 0.f, 0.f};

  const int wm = w & 3, wn = w >> 2;   // off: 4 M-waves (32 rows) x 2 N-waves (64 cols)

  // stage swizzle: chunk c -> row = c>>3, phys = c&7, logical kc = phys ^ (row&7)
  int arow[2], acol[2];
#pragma unroll
  for (int i = 0; i < 2; ++i) {                     // A: 1024 chunks / 512 thr
    int c = tid + i * 512;
    arow[i] = c >> 3;
    acol[i] = (((c & 7) ^ ((c >> 3) & 7))) * 8;
  }
  // read swizzle: row&7 = lane&7 (row = 16*b + (lane&15));
  // logical chunk lc = mk*4 + (lane>>4); phys = lc ^ (lane&7)
  const int lanerow = (lane & 15) * 64;
  const int ph0 = (((lane >> 4)) ^ (lane & 7)) * 8;        // mk = 0
  const int ph1 = (((lane >> 4) + 4) ^ (lane & 7)) * 8;    // mk = 1

  for (int k0 = 0; k0 < DORI; k0 += 64) {
#pragma unroll
    for (int i = 0; i < 2; ++i)
      gload_lds16(Ab + (size_t)arow[i] * DORI + k0 + acol[i], As + (tid + i * 512) * 8);
    if (small) {
      if (tid < 256)                                // B: 32 rows x 8 chunks
        gload_lds16(Bb + (size_t)(tid >> 3) * DORI + k0 + (((tid & 7) ^ ((tid >> 3) & 7)) * 8),
                    Bs + tid * 8);
    } else {
#pragma unroll
      for (int i = 0; i < 2; ++i)
        gload_lds16(Bb + (size_t)arow[i] * DORI + k0 + acol[i], Bs + (tid + i * 512) * 8);
    }
    __syncthreads();
    if (small) {
#pragma unroll
      for (int mk = 0; mk < 2; ++mk) {
        const int ph = mk ? ph1 : ph0;
        s16x8 af = *(const s16x8*)(As + (w * 16) * 64 + lanerow + ph);
        s16x8 bf[2];
#pragma unroll
        for (int j = 0; j < 2; ++j)
          bf[j] = *(const s16x8*)(Bs + (j * 16) * 64 + lanerow + ph);
#pragma unroll
        for (int j = 0; j < 2; ++j)
          accS[j] = __builtin_amdgcn_mfma_f32_16x16x32_bf16(af, bf[j], accS[j], 0, 0, 0);
      }
    } else {
#pragma unroll
      for (int mk = 0; mk < 2; ++mk) {
        const int ph = mk ? ph1 : ph0;
        s16x8 af[2], bf[4];
#pragma unroll
        for (int i = 0; i < 2; ++i)
          af[i] = *(const s16x8*)(As + (wm * 32 + i * 16) * 64 + lanerow + ph);
#pragma unroll
        for (int j = 0; j < 4; ++j)
          bf[j] = *(const s16x8*)(Bs + (wn * 64 + j * 16) * 64 + lanerow + ph);
#pragma unroll
        for (int i = 0; i < 2; ++i)
#pragma unroll
          for (int j = 0; j < 4; ++j)
            accM[i][j] = __builtin_amdgcn_mfma_f32_16x16x32_bf16(af[i], bf[j], accM[i][j], 0, 0, 0);
      }
    }
    __syncthreads();
  }

  if (small) {
#pragma unroll
    for (int j = 0; j < 2; ++j)
#pragma unroll
      for (int q = 0; q < 4; ++q) {
        const int row = tileM + w * 16 + (lane >> 4) * 4 + q;
        const int col = j * 16 + (lane & 15);
        const size_t an = (size_t)bz * NN + row;
        float v = accS[j][q];
        smallf[an * 32 + col] = v;
        if (col >= 8 && col <= 28) cls_out[an * 21 + (col - 8)] = v;
      }
  } else {
    const int r0 = tileM + wm * 32 + (lane >> 4) * 4;
    const int c0 = bx * 128 + wn * 64 + (lane & 15);
#pragma unroll
    for (int i = 0; i < 2; ++i)
#pragma unroll
      for (int j = 0; j < 4; ++j)
#pragma unroll
        for (int q = 0; q < 4; ++q)
          offb[((size_t)bz * NN + r0 + i * 16 + q) * DAPP + c0 + j * 16] =
              f2b(fmaxf(accM[i][j][q], 0.f));
  }
}

// ================= bf16 GEMM, glds staging, 2-phase dbuf (key path) ================
template<int BM, int BN, int WM, int WN, bool RELU, bool OUTBF, bool SWZ>
__global__ __launch_bounds__(WM * WN * 64)
void gemm_glds(const u16* __restrict__ A, long sA, const u16* __restrict__ B, long sB,
               void* __restrict__ Cv, long sC, int N, int K) {
  constexpr int THREADS = WM * WN * 64;
  constexpr int WTM = BM / WM, WTN = BN / WN;
  constexpr int FM = WTM / 16, FN = WTN / 16;
  constexpr int ACHN = BM * 4, BCHN = BN * 4;
  constexpr int ACH = (ACHN + THREADS - 1) / THREADS;
  constexpr int BCH = (BCHN + THREADS - 1) / THREADS;
  constexpr bool AFULL = (ACHN % THREADS) == 0, BFULL = (BCHN % THREADS) == 0;

  __shared__ __align__(16) u16 As[2][BM * 32];
  __shared__ __align__(16) u16 Bs[2][BN * 32];

  int bx = blockIdx.x, by = blockIdx.y, bz = blockIdx.z;
  if constexpr (SWZ) {
    int gx = gridDim.x, gy = gridDim.y;
    int h = bx + gx * (by + gy * bz);
    int nwg = gx * gy * (int)gridDim.z;
    int cpx = nwg >> 3;
    int l = (h & 7) * cpx + (h >> 3);
    bx = l % gx; l /= gx; by = l % gy; bz = l / gy;
  }

  const int tid = threadIdx.x, lane = tid & 63, wave = tid >> 6;
  const int wm = wave % WM, wn = wave / WM;
  const int tileN = bx * BN, tileM = by * BM;
  const u16* Ab = A + (size_t)bz * sA + (size_t)tileM * K;
  const u16* Bb = B + (size_t)bz * sB + (size_t)tileN * K;

  f32x4 acc[FM][FN];
#pragma unroll
  for (int i = 0; i < FM; ++i)
#pragma unroll
    for (int j = 0; j < FN; ++j) acc[i][j] = (f32x4){0.f, 0.f, 0.f, 0.f};

  auto stage = [&](int buf, int k0) {
#pragma unroll
    for (int i = 0; i < ACH; ++i) {
      int c = tid + i * THREADS;
      if (AFULL || c < ACHN)
        gload_lds16(Ab + (size_t)(c >> 2) * K + k0 + (c & 3) * 8, As[buf] + c * 8);
    }
#pragma unroll
    for (int i = 0; i < BCH; ++i) {
      int c = tid + i * THREADS;
      if (BFULL || c < BCHN)
        gload_lds16(Bb + (size_t)(c >> 2) * K + k0 + (c & 3) * 8, Bs[buf] + c * 8);
    }
  };

  stage(0, 0);
  __syncthreads();
  int cur = 0;
  for (int k0 = 0; k0 < K; k0 += 32) {
    if (k0 + 32 < K) stage(cur ^ 1, k0 + 32);
    const u16* Arow = As[cur] + (wm * WTM + (lane & 15)) * 32 + (lane >> 4) * 8;
    const u16* Brow = Bs[cur] + (wn * WTN + (lane & 15)) * 32 + (lane >> 4) * 8;
    s16x8 af[FM], bfr[FN];
#pragma unroll
    for (int i = 0; i < FM; ++i) af[i] = *(const s16x8*)(Arow + i * 16 * 32);
#pragma unroll
    for (int j = 0; j < FN; ++j) bfr[j] = *(const s16x8*)(Brow + j * 16 * 32);
#pragma unroll
    for (int i = 0; i < FM; ++i)
#pragma unroll
      for (int j = 0; j < FN; ++j)
        acc[i][j] = __builtin_amdgcn_mfma_f32_16x16x32_bf16(af[i], bfr[j], acc[i][j], 0, 0, 0);
    __syncthreads();
    cur ^= 1;
  }

  const int r0 = tileM + wm * WTM + (lane >> 4) * 4;
  const int c0 = tileN + wn * WTN + (lane & 15);
#pragma unroll
  for (int i = 0; i < FM; ++i)
#pragma unroll
    for (int j = 0; j < FN; ++j)
#pragma unroll
      for (int q = 0; q < 4; ++q) {
        float v = acc[i][j][q];
        if (RELU) v = fmaxf(v, 0.f);
        size_t idx = (size_t)bz * sC + (size_t)(r0 + i * 16 + q) * N + (c0 + j * 16);
        if (OUTBF) ((u16*)Cv)[idx] = f2b(v);
        else       ((float*)Cv)[idx] = v;
      }
}

// ================= fallback gemm (A = f32, reg-staged pack) ========================
template<int BM, int BN, int WM, int WN, bool RELU, bool OUTBF>
__global__ __launch_bounds__(WM * WN * 64)
void gemm_af32(const float* __restrict__ Av, const float* __restrict__ A2v, long sA,
               const u16* __restrict__ B, long sB,
               void* __restrict__ Cv, long sC, int N, int K) {
  constexpr int THREADS = WM * WN * 64;
  constexpr int WTM = BM / WM, WTN = BN / WN;
  constexpr int FM = WTM / 16, FN = WTN / 16;
  constexpr int ACH = (BM * 4) / THREADS;
  constexpr int BCHN = BN * 4;
  constexpr int BCH = (BCHN + THREADS - 1) / THREADS;
  constexpr bool BFULL = (BCHN % THREADS) == 0;

  __shared__ __align__(16) u16 As[BM * 32];
  __shared__ __align__(16) u16 Bs[BN * 32];

  const int tid = threadIdx.x, lane = tid & 63, wave = tid >> 6;
  const int wm = wave % WM, wn = wave / WM;
  const int tileN = blockIdx.x * BN, tileM = blockIdx.y * BM;
  const int batch = blockIdx.z;
  const float* base = (batch < 9) ? (Av + (size_t)batch * sA) : A2v;
  const float* Ab32 = base + (size_t)tileM * K;
  const u16* Bb = B + (size_t)batch * sB + (size_t)tileN * K;

  f32x4 acc[FM][FN];
#pragma unroll
  for (int i = 0; i < FM; ++i)
#pragma unroll
    for (int j = 0; j < FN; ++j) acc[i][j] = (f32x4){0.f, 0.f, 0.f, 0.f};

  uint4 ra[ACH], rb[BCH];
  auto load_t = [&](int k0) {
#pragma unroll
    for (int i = 0; i < ACH; ++i) {
      int c = tid + i * THREADS;
      const float* s = Ab32 + (size_t)(c >> 2) * K + k0 + (c & 3) * 8;
      ra[i] = pack8(*(const float4*)s, *(const float4*)(s + 4));
    }
#pragma unroll
    for (int i = 0; i < BCH; ++i) {
      int c = tid + i * THREADS;
      if (BFULL || c < BCHN)
        rb[i] = *(const uint4*)(Bb + (size_t)(c >> 2) * K + k0 + (c & 3) * 8);
    }
  };

  load_t(0);
  const u16* Arow = As + (wm * WTM + (lane & 15)) * 32 + (lane >> 4) * 8;
  const u16* Brow = Bs + (wn * WTN + (lane & 15)) * 32 + (lane >> 4) * 8;

  for (int k0 = 0; k0 < K; k0 += 32) {
    __syncthreads();
#pragma unroll
    for (int i = 0; i < ACH; ++i)
      *(uint4*)(As + (size_t)(tid + i * THREADS) * 8) = ra[i];
#pragma unroll
    for (int i = 0; i < BCH; ++i) {
      int c = tid + i * THREADS;
      if (BFULL || c < BCHN) *(uint4*)(Bs + (size_t)c * 8) = rb[i];
    }
    __syncthreads();
    if (k0 + 32 < K) load_t(k0 + 32);
    s16x8 af[FM], bfr[FN];
#pragma unroll
    for (int i = 0; i < FM; ++i) af[i] = *(const s16x8*)(Arow + i * 16 * 32);
#pragma unroll
    for (int j = 0; j < FN; ++j) bfr[j] = *(const s16x8*)(Brow + j * 16 * 32);
#pragma unroll
    for (int i = 0; i < FM; ++i)
#pragma unroll
      for (int j = 0; j < FN; ++j)
        acc[i][j] = __builtin_amdgcn_mfma_f32_16x16x32_bf16(af[i], bfr[j], acc[i][j], 0, 0, 0);
  }

  const int r0 = tileM + wm * WTM + (lane >> 4) * 4;
  const int c0 = tileN + wn * WTN + (lane & 15);
#pragma unroll
  for (int i = 0; i < FM; ++i)
#pragma unroll
    for (int j = 0; j < FN; ++j)
#pragma unroll
      for (int q = 0; q < 4; ++q) {
        float v = acc[i][j][q];
        if (RELU) v = fmaxf(v, 0.f);
        size_t idx = (size_t)batch * sC + (size_t)(r0 + i * 16 + q) * N + (c0 + j * 16);
        if (OUTBF) ((u16*)Cv)[idx] = f2b(v);
        else       ((float*)Cv)[idx] = v;
      }
}

// ================= cls copy (fallback path only) ===================================
__global__ __launch_bounds__(256) void cls_copy(const float* __restrict__ smallf,
                                                float* __restrict__ o) {
  int i = blockIdx.x * blockDim.x + threadIdx.x;
  if (i >= AN * NN * NCLS) return;
  int an = i / NCLS, c = i % NCLS;
  o[i] = smallf[(size_t)an * 32 + 8 + c];
}

// ================= fused q-projection + beta epilogue, 2-phase dbuf ================
__global__ __launch_bounds__(256) void gemm2qb(const u16* __restrict__ offb,
                                               const u16* __restrict__ Wq,
                                               const float* __restrict__ keyf,
                                               const float* __restrict__ ious,
                                               float* __restrict__ betaf,
                                               float* __restrict__ betac) {
  constexpr int BM = 128, BN = 160;
  __shared__ __align__(16) u16 As[2][BM * 32];
  __shared__ __align__(16) u16 Bs[2][BN * 32];
  const int tid = threadIdx.x, lane = tid & 63, wave = tid >> 6;  // 4 waves on M
  const int tileM = blockIdx.x * BM;
  const int a = blockIdx.y;
  const u16* Ab = offb + ((size_t)a * NN + tileM) * DAPP;
  const u16* Bb = Wq + (size_t)a * QCOLS * DAPP;

  f32x4 acc[2][10];
#pragma unroll
  for (int i = 0; i < 2; ++i)
#pragma unroll
    for (int j = 0; j < 10; ++j) acc[i][j] = (f32x4){0.f, 0.f, 0.f, 0.f};

  auto stage = [&](int buf, int k0) {
#pragma unroll
    for (int i = 0; i < 2; ++i) {          // ACHN = 512
      int c = tid + i * 256;
      gload_lds16(Ab + (size_t)(c >> 2) * DAPP + k0 + (c & 3) * 8, As[buf] + c * 8);
    }
#pragma unroll
    for (int i = 0; i < 3; ++i) {          // BCHN = 640
      int c = tid + i * 256;
      if (c < 640)
        gload_lds16(Bb + (size_t)(c >> 2) * DAPP + k0 + (c & 3) * 8, Bs[buf] + c * 8);
    }
  };

  stage(0, 0);
  __syncthreads();
  int cur = 0;
  for (int k0 = 0; k0 < DAPP; k0 += 32) {
    if (k0 + 32 < DAPP) stage(cur ^ 1, k0 + 32);
    const u16* Arow = As[cur] + (wave * 32 + (lane & 15)) * 32 + (lane >> 4) * 8;
    const u16* Brow = Bs[cur] + (lane & 15) * 32 + (lane >> 4) * 8;
    s16x8 af[2], bfr[10];
#pragma unroll
    for (int i = 0; i < 2; ++i) af[i] = *(const s16x8*)(Arow + i * 16 * 32);
#pragma unroll
    for (int j = 0; j < 10; ++j) bfr[j] = *(const s16x8*)(Brow + j * 16 * 32);
#pragma unroll
    for (int i = 0; i < 2; ++i)
#pragma unroll
      for (int j = 0; j < 10; ++j)
        acc[i][j] = __builtin_amdgcn_mfma_f32_16x16x32_bf16(af[i], bfr[j], acc[i][j], 0, 0, 0);
    __syncthreads();
    cur ^= 1;
  }

  const float scale = 0.17677669529663687f;  // 1/sqrt(32)
  const int cg = lane & 15;
#pragma unroll
  for (int i = 0; i < 2; ++i)
#pragma unroll
    for (int q = 0; q < 4; ++q) {
      const int row = tileM + wave * 32 + i * 16 + (lane >> 4) * 4 + q;
      const float* kr = keyf + (size_t)row * QCOLS;
      float m = 0.f;
#pragma unroll
      for (int j = 0; j < 8; ++j) m += acc[i][j][q] * kr[cg + j * 16];
      float cl = acc[i][8][q] * kr[128 + cg] + acc[i][9][q] * kr[144 + cg];
      m += __shfl_xor(m, 4); m += __shfl_xor(m, 8);
      cl += __shfl_xor(cl, 1); cl += __shfl_xor(cl, 2);
      cl += __shfl_xor(cl, 4); cl += __shfl_xor(cl, 8);
      const float iou = ious[(size_t)a * NN + row];
      if (cg < 4)  betaf[((size_t)a * NN + row) * 4 + (lane & 3)] = m * scale - iou;
      if (cg == 0) betac[(size_t)a * NN + row] = cl * scale - iou;
    }
}

// ================= softmaxes + outputs, thread per (n,c) ===========================
__global__ __launch_bounds__(256) void finalize(const float* __restrict__ smallf,
                                                const float* __restrict__ beta_ws,
                                                const float* __restrict__ betac_ws,
                                                const float* __restrict__ delta_rois,
                                                float* __restrict__ out) {
  int t = blockIdx.x * 256 + threadIdx.x;      // grid = NN*4/256 = 64
  if (t >= NN * 4) return;
  const int n = t >> 2, c = t & 3;

  {
    float al[9], be[9], dp[9];
    float mA = -1e30f, mB = -1e30f;
    for (int a = 0; a < 9; ++a) {
      size_t an = (size_t)a * NN + n;
      al[a] = smallf[an * 32 + c];
      float off_ = smallf[an * 32 + 4 + c];
      dp[a] = delta_rois[an * 5 + 1 + c] + off_;
      be[a] = beta_ws[an * 4 + c];
      mA = fmaxf(mA, al[a]); mB = fmaxf(mB, be[a]);
    }
    float eA[9], eB[9], sA = 0.f, sB = 0.f;
    for (int a = 0; a < 9; ++a) {
      eA[a] = expf(al[a] - mA); sA += eA[a];
      eB[a] = expf(be[a] - mB); sB += eB[a];
    }
    float rA = 1.f / sA, rB = 1.f / sB;
    float ov = 0.f, obv = 0.f;
    for (int a = 0; a < 9; ++a) {
      size_t an = (size_t)a * NN + n;
      float as_ = eA[a] * rA, bs_ = eB[a] * rB;
      out[O2 + an * 4 + c] = as_;
      out[O3 + an * 4 + c] = bs_;
      out[O4 + an * 4 + c] = dp[a];
      out[O5 + an * 4 + c] = dp[a];
      out[O6 + an * 4 + c] = al[a];
      out[O7 + an * 4 + c] = be[a];
      ov += dp[a] * as_; obv += dp[a] * bs_;
    }
    out[O0 + (size_t)n * 4 + c] = ov;
    out[O1 + (size_t)n * 4 + c] = obv;
  }

  if (c == 0) {
    float ac[9], bc[9];
    float mA = -1e30f, mB = -1e30f;
    for (int a = 0; a < 9; ++a) {
      size_t an = (size_t)a * NN + n;
      ac[a] = smallf[an * 32 + 29];
      bc[a] = betac_ws[an];
      mA = fmaxf(mA, ac[a]); mB = fmaxf(mB, bc[a]);
    }
    float eA[9], eB[9], sA = 0.f, sB = 0.f;
    for (int a = 0; a < 9; ++a) {
      eA[a] = expf(ac[a] - mA); sA += eA[a];
      eB[a] = expf(bc[a] - mB); sB += eB[a];
    }
    float rA = 1.f / sA, rB = 1.f / sB;
    for (int a = 0; a < 9; ++a) {
      size_t an = (size_t)a * NN + n;
      out[O9 + an]  = eA[a] * rA;
      out[O10 + an] = eB[a] * rB;
      out[O11 + an] = ac[a];
      out[O12 + an] = bc[a];
    }
  }
}

extern "C" void kernel_launch(void* const* d_in, const int* in_sizes, int n_in,
                              void* d_out, int out_size, void* d_ws, size_t ws_size,
                              hipStream_t stream) {
  const float* delta_rois = (const float*)d_in[1];
  const float* features   = (const float*)d_in[2];
  const float* gt_features= (const float*)d_in[3];
  const float* ious       = (const float*)d_in[4];
  const float* att        = (const float*)d_in[5];
  const float* w_k        = (const float*)d_in[6];
  const float* w_q        = (const float*)d_in[7];
  const float* alpha_w    = (const float*)d_in[8];
  const float* bbox       = (const float*)d_in[9];
  const float* w_k_cls    = (const float*)d_in[10];
  const float* w_q_cls    = (const float*)d_in[11];
  const float* alpha_w_cls= (const float*)d_in[12];
  const float* cls_w      = (const float*)d_in[13];
  float* out = (float*)d_out;

  char* ws = (char*)d_ws;
  u16* attB    = (u16*)ws;   ws += (size_t)DAPP * DORI * 2;       // 2.1 MB
  u16* Wq      = (u16*)ws;   ws += (size_t)NB * QCOLS * DAPP * 2; // 1.6 MB
  u16* Wsmall  = (u16*)ws;   ws += (size_t)AN * 32 * DORI * 2;    // 1.2 MB
  u16* offb    = (u16*)ws;   ws += (size_t)NB * NN * DAPP * 2;    // 42 MB (batch9 = gt_off)
  float* smallf= (float*)ws; ws += (size_t)AN * NN * 32 * 4;      // 4.7 MB
  float* keyf  = (float*)ws; ws += (size_t)NN * QCOLS * 4;        // 2.6 MB
  float* betaf = (float*)ws; ws += (size_t)AN * NN * 4 * 4;       // 2.4 MB
  float* betac = (float*)ws; ws += (size_t)AN * NN * 4;           // 0.15 MB
  size_t base_bytes = (size_t)(ws - (char*)d_ws);
  size_t featB_bytes = (size_t)NB * NN * DORI * 2;                // 168 MB
  bool big = ws_size >= base_bytes + featB_bytes;
  u16* featB = big ? (u16*)ws : nullptr;

  // 1. fused prep + full-feature cast (one launch)
  prep_cast<<<PREP_TOTAL, 256, 0, stream>>>(features, att, w_q, w_q_cls, w_k, w_k_cls,
                                            alpha_w, bbox, alpha_w_cls, cls_w,
                                            gt_features, featB, attB, Wq, Wsmall);

  if (big) {
    // 2. off + smallf + cls, 128-tile, BK=64, 8 waves x 32x64, panel-local swizzle
    dim3 gm(5, 32, NB);
    gemm_main<<<gm, 512, 0, stream>>>(featB, attB, Wsmall, offb, smallf, out + O8);
  } else {
    dim3 g1(DAPP / 128, NN / 128, NB);
    gemm_af32<128, 128, 2, 2, true, true><<<g1, 256, 0, stream>>>(
        features, gt_features, (long)NN * DORI, attB, 0, offb, (long)NN * DAPP, DAPP, DORI);
    dim3 gsm(1, NN / 128, AN);
    gemm_af32<128, 32, 4, 1, false, false><<<gsm, 256, 0, stream>>>(
        features, nullptr, (long)NN * DORI, Wsmall, (long)32 * DORI,
        smallf, (long)NN * 32, 32, DORI);
    cls_copy<<<(AN * NN * NCLS + 255) / 256, 256, 0, stream>>>(smallf, out + O8);
  }

  // 3. key = gt_off @ Wq[9]^T (batch 9) -> keyf f32
  dim3 gk(QCOLS / 32, NN / 128, 1);
  gemm_glds<128, 32, 4, 1, false, false, false><<<gk, 256, 0, stream>>>(
      offb + (size_t)9 * NN * DAPP, 0, Wq + (size_t)9 * QCOLS * DAPP, 0,
      keyf, 0, QCOLS, DAPP);

  // 4. fused q-projection + beta (batches 0-8)
  dim3 g2(NN / 128, AN, 1);
  gemm2qb<<<g2, 256, 0, stream>>>(offb, Wq, keyf, ious, betaf, betac);

  // 5. softmaxes + outputs
  finalize<<<NN * 4 / 256, 256, 0, stream>>>(smallf, betaf, betac, delta_rois, out);
}